// Round 1
// baseline (1200.824 us; speedup 1.0000x reference)
//
#include <hip/hip_runtime.h>
#include <hip/hip_bf16.h>
#include <cstdint>

#define NEG_SLOPE 0.2f

// ---------------- build x = concat(emb[ids], degrees) ----------------
__global__ void build_x_kernel(const int* __restrict__ ids, const float* __restrict__ degs,
                               const float* __restrict__ emb, float* __restrict__ x, int Nn)
{
    int node = blockIdx.x * (blockDim.x >> 6) + (threadIdx.x >> 6);
    int lane = threadIdx.x & 63;
    if (node >= Nn) return;
    int id = ids[node];
    float v;
    if (lane < 62) v = emb[(size_t)id * 62 + lane];
    else           v = degs[node * 2 + (lane - 62)];
    x[(size_t)node * 64 + lane] = v;
}

// ---------------- CSR build ----------------
__global__ void hist_dst_kernel(const int* __restrict__ edst, int* __restrict__ cnt, int E0, int E2)
{
    int e = blockIdx.x * blockDim.x + threadIdx.x;
    if (e >= E2) return;
    int d = (e < E0) ? edst[e] : (e - E0);
    atomicAdd(&cnt[d], 1);
}

__global__ void batch_hist_kernel(const int* __restrict__ batch, int* __restrict__ gcnt, int Nn)
{
    int n = blockIdx.x * blockDim.x + threadIdx.x;
    if (n < Nn) atomicAdd(&gcnt[batch[n]], 1);
}

__global__ void scan_kernel(const int* __restrict__ cnt, int* __restrict__ row_off,
                            int* __restrict__ cursor, int Nn, int total)
{
    __shared__ int part[1024];
    int t = threadIdx.x;
    const int CH = (Nn + 1023) / 1024;
    int base = t * CH;
    int sum = 0;
    for (int i = 0; i < CH; ++i) {
        int idx = base + i;
        if (idx < Nn) sum += cnt[idx];
    }
    part[t] = sum;
    __syncthreads();
    for (int off = 1; off < 1024; off <<= 1) {
        int v = (t >= off) ? part[t - off] : 0;
        __syncthreads();
        part[t] += v;
        __syncthreads();
    }
    int run = (t == 0) ? 0 : part[t - 1];
    for (int i = 0; i < CH; ++i) {
        int idx = base + i;
        if (idx < Nn) {
            row_off[idx] = run;
            cursor[idx] = run;
            run += cnt[idx];
        }
    }
    if (t == 1023) row_off[Nn] = total;
}

__global__ void scatter_kernel(const int* __restrict__ esrc, const int* __restrict__ edst,
                               int* __restrict__ cursor, int* __restrict__ csr_src,
                               int* __restrict__ csr_eid, int E0, int E2)
{
    int e = blockIdx.x * blockDim.x + threadIdx.x;
    if (e >= E2) return;
    int s, d;
    if (e < E0) { s = esrc[e]; d = edst[e]; }
    else        { s = d = e - E0; }
    int pos = atomicAdd(&cursor[d], 1);
    csr_src[pos] = s;
    csr_eid[pos] = e;
}

// ---------------- fp32 GEMM: H[n,f] = sum_k X[n,k] * W[f,k] ----------------
template<int BK>
__global__ void gemm_tn(const float* __restrict__ X, const float* __restrict__ W,
                        float* __restrict__ Hout, int Nn, int K, int F)
{
    __shared__ float As[BK][64 + 1];
    __shared__ float Bs[BK][64 + 1];
    int bn = blockIdx.x * 64;
    int bf = blockIdx.y * 64;
    int tid = threadIdx.x;          // 256 threads
    int tx = tid & 15, ty = tid >> 4;
    float acc[4][4];
#pragma unroll
    for (int i = 0; i < 4; ++i)
#pragma unroll
        for (int j = 0; j < 4; ++j) acc[i][j] = 0.f;

    for (int k0 = 0; k0 < K; k0 += BK) {
#pragma unroll
        for (int i = 0; i < (64 * BK) / 256; ++i) {
            int idx = tid + i * 256;
            int r = idx / BK, c = idx % BK;
            int n = bn + r;
            As[c][r] = (n < Nn) ? X[(size_t)n * K + k0 + c] : 0.f;
            Bs[c][r] = W[(size_t)(bf + r) * K + k0 + c];
        }
        __syncthreads();
#pragma unroll
        for (int kk = 0; kk < BK; ++kk) {
            float a[4], b[4];
#pragma unroll
            for (int i = 0; i < 4; ++i) a[i] = As[kk][ty * 4 + i];
#pragma unroll
            for (int j = 0; j < 4; ++j) b[j] = Bs[kk][tx * 4 + j];
#pragma unroll
            for (int i = 0; i < 4; ++i)
#pragma unroll
                for (int j = 0; j < 4; ++j) acc[i][j] += a[i] * b[j];
        }
        __syncthreads();
    }
#pragma unroll
    for (int i = 0; i < 4; ++i) {
        int n = bn + ty * 4 + i;
        if (n >= Nn) break;
#pragma unroll
        for (int j = 0; j < 4; ++j)
            Hout[(size_t)n * F + bf + tx * 4 + j] = acc[i][j];
    }
}

// ---------------- per-node attention coefficients ----------------
template<int H>
__global__ void attn_scores_kernel(const float* __restrict__ Hb, const float* __restrict__ as,
                                   const float* __restrict__ ad, float* __restrict__ a_s,
                                   float* __restrict__ a_d, int Nn)
{
    constexpr int F = H * 64;
    constexpr int VEC = F / 64;
    constexpr int GS = 64 / H;   // lanes per head group
    int node = blockIdx.x * (blockDim.x >> 6) + (threadIdx.x >> 6);
    int lane = threadIdx.x & 63;
    if (node >= Nn) return;
    float ps = 0.f, pd = 0.f;
    const float* hrow = Hb + (size_t)node * F + lane * VEC;
#pragma unroll
    for (int k = 0; k < VEC; ++k) {
        float hv = hrow[k];
        ps += hv * as[lane * VEC + k];
        pd += hv * ad[lane * VEC + k];
    }
#pragma unroll
    for (int off = GS / 2; off >= 1; off >>= 1) {
        ps += __shfl_xor(ps, off, 64);
        pd += __shfl_xor(pd, off, 64);
    }
    if ((lane & (GS - 1)) == 0) {
        int h = lane / GS;
        a_s[(size_t)node * H + h] = ps;
        a_d[(size_t)node * H + h] = pd;
    }
}

// ---------------- raw edge scores (leaky relu) ----------------
template<int H>
__global__ void edge_scores_kernel(const int* __restrict__ esrc, const int* __restrict__ edst,
                                   const float* __restrict__ a_s, const float* __restrict__ a_d,
                                   float* __restrict__ el, int E0, int E2)
{
    int e = blockIdx.x * blockDim.x + threadIdx.x;
    if (e >= E2) return;
    int s, d;
    if (e < E0) { s = esrc[e]; d = edst[e]; }
    else        { s = d = e - E0; }
#pragma unroll
    for (int h = 0; h < H; ++h) {
        float v = a_s[(size_t)s * H + h] + a_d[(size_t)d * H + h];
        el[(size_t)e * H + h] = (v > 0.f) ? v : NEG_SLOPE * v;
    }
}

// ---------------- per-dst-node softmax + weighted aggregation ----------------
template<int H>
__global__ void aggregate_kernel(const float* __restrict__ Hb, const float* __restrict__ el,
                                 const int* __restrict__ row_off, const int* __restrict__ csr_src,
                                 const int* __restrict__ csr_eid, const float* __restrict__ bias,
                                 float* __restrict__ out, int Nn)
{
    constexpr int F = H * 64;
    constexpr int VEC = F / 64;
    int node = blockIdx.x * (blockDim.x >> 6) + (threadIdx.x >> 6);
    int lane = threadIdx.x & 63;
    if (node >= Nn) return;
    int start = row_off[node], end = row_off[node + 1];

    float m[H], s[H];
#pragma unroll
    for (int h = 0; h < H; ++h) { m[h] = -1e30f; s[h] = 0.f; }

    // pass A: per-head max over incoming edges (lane-parallel)
    for (int j = start + lane; j < end; j += 64) {
        int eid = csr_eid[j];
#pragma unroll
        for (int h = 0; h < H; ++h) m[h] = fmaxf(m[h], el[(size_t)eid * H + h]);
    }
#pragma unroll
    for (int off = 32; off >= 1; off >>= 1)
#pragma unroll
        for (int h = 0; h < H; ++h) m[h] = fmaxf(m[h], __shfl_xor(m[h], off, 64));

    // pass B: sum of exp
    for (int j = start + lane; j < end; j += 64) {
        int eid = csr_eid[j];
#pragma unroll
        for (int h = 0; h < H; ++h) s[h] += __expf(el[(size_t)eid * H + h] - m[h]);
    }
#pragma unroll
    for (int off = 32; off >= 1; off >>= 1)
#pragma unroll
        for (int h = 0; h < H; ++h) s[h] += __shfl_xor(s[h], off, 64);

    int head; float mh, sh;
    if (H == 1) { head = 0; mh = m[0]; sh = s[0]; }
    else {
        head = lane >> 4;
        mh = (head == 0) ? m[0] : (head == 1) ? m[1] : (head == 2) ? m[2] : m[3];
        sh = (head == 0) ? s[0] : (head == 1) ? s[1] : (head == 2) ? s[2] : s[3];
    }
    float invh = 1.f / (sh + 1e-16f);

    // pass C: weighted sum of h[src] (whole wave per edge; coalesced 256/64-float reads)
    float acc[VEC];
#pragma unroll
    for (int k = 0; k < VEC; ++k) acc[k] = 0.f;
    for (int j = start; j < end; ++j) {
        int sn = csr_src[j];
        int eid = csr_eid[j];
        float ex = __expf(el[(size_t)eid * H + head] - mh);
        const float* hp = Hb + (size_t)sn * F + lane * VEC;
#pragma unroll
        for (int k = 0; k < VEC; ++k) acc[k] += ex * hp[k];
    }
#pragma unroll
    for (int k = 0; k < VEC; ++k) {
        int f = lane * VEC + k;
        float v = acc[k] * invh + bias[f];
        out[(size_t)node * F + f] = (v > 0.f) ? v : 0.f;   // fused ReLU
    }
}

// ---------------- global mean pool (sums) ----------------
__global__ void pool_kernel(const float* __restrict__ x, const int* __restrict__ batch,
                            float* __restrict__ gsums, int Nn)
{
    int lane = threadIdx.x;        // blockDim = 64
    int n0 = blockIdx.x * 64;
    if (n0 >= Nn) return;
    int nend = min(n0 + 64, Nn);
    float acc = 0.f;
    int gcur = batch[n0];
    for (int n = n0; n < nend; ++n) {
        int g = batch[n];
        if (g != gcur) {
            atomicAdd(&gsums[gcur * 64 + lane], acc);
            acc = 0.f;
            gcur = g;
        }
        acc += x[(size_t)n * 64 + lane];
    }
    atomicAdd(&gsums[gcur * 64 + lane], acc);
}

// ---------------- final linear ----------------
__global__ void final_kernel(const float* __restrict__ gsums, const int* __restrict__ gcnt,
                             const float* __restrict__ linW, const float* __restrict__ linb,
                             float* __restrict__ out, int G)
{
    int t = threadIdx.x;
    if (t >= G * 10) return;
    int g = t / 10, j = t % 10;
    float cnt = (float)max(gcnt[g], 1);
    float acc = 0.f;
#pragma unroll
    for (int c = 0; c < 64; ++c) acc += gsums[g * 64 + c] * linW[j * 64 + c];
    out[g * 10 + j] = acc / cnt + linb[j];
}

extern "C" void kernel_launch(void* const* d_in, const int* in_sizes, int n_in,
                              void* d_out, int out_size, void* d_ws, size_t ws_size,
                              hipStream_t stream)
{
    const int*   x_ids    = (const int*)d_in[0];
    const float* degrees  = (const float*)d_in[1];
    const int*   edge_src = (const int*)d_in[2];
    const int*   edge_dst = (const int*)d_in[3];
    const int*   batch    = (const int*)d_in[4];
    const float* emb      = (const float*)d_in[5];
    const float* W1  = (const float*)d_in[6];
    const float* as1 = (const float*)d_in[7];
    const float* ad1 = (const float*)d_in[8];
    const float* b1  = (const float*)d_in[9];
    const float* W2  = (const float*)d_in[10];
    const float* as2 = (const float*)d_in[11];
    const float* ad2 = (const float*)d_in[12];
    const float* b2  = (const float*)d_in[13];
    const float* W3  = (const float*)d_in[14];
    const float* as3 = (const float*)d_in[15];
    const float* ad3 = (const float*)d_in[16];
    const float* b3  = (const float*)d_in[17];
    const float* linW = (const float*)d_in[18];
    const float* linb = (const float*)d_in[19];

    const int N  = in_sizes[0];
    const int E0 = in_sizes[2];
    const int E2 = E0 + N;
    const int G  = out_size / 10;

    char* p = (char*)d_ws;
    size_t off = 0;
    auto take = [&](size_t bytes) {
        void* q = p + off;
        off = (off + bytes + 255) & ~(size_t)255;
        return q;
    };
    float* xA      = (float*)take((size_t)N * 256 * 4);
    float* xB      = (float*)take((size_t)N * 256 * 4);
    float* a_s     = (float*)take((size_t)N * 4 * 4);
    float* a_d     = (float*)take((size_t)N * 4 * 4);
    float* el      = (float*)take((size_t)E2 * 4 * 4);
    int*   cnt     = (int*)take((size_t)N * 4);
    int*   row_off = (int*)take((size_t)(N + 1) * 4);
    int*   cursor  = (int*)take((size_t)N * 4);
    int*   csr_src = (int*)take((size_t)E2 * 4);
    int*   csr_eid = (int*)take((size_t)E2 * 4);
    float* gsums   = (float*)take((size_t)G * 64 * 4);
    int*   gcnt    = (int*)take((size_t)G * 4);

    hipMemsetAsync(cnt, 0, (size_t)N * 4, stream);
    hipMemsetAsync(gsums, 0, (size_t)G * 64 * 4, stream);
    hipMemsetAsync(gcnt, 0, (size_t)G * 4, stream);

    const int nodeBlocks4 = (N + 3) / 4;          // 4 waves (nodes) per 256-thread block
    const int edgeBlocks  = (E2 + 255) / 256;

    build_x_kernel<<<nodeBlocks4, 256, 0, stream>>>(x_ids, degrees, emb, xA, N);
    hist_dst_kernel<<<edgeBlocks, 256, 0, stream>>>(edge_dst, cnt, E0, E2);
    batch_hist_kernel<<<(N + 255) / 256, 256, 0, stream>>>(batch, gcnt, N);
    scan_kernel<<<1, 1024, 0, stream>>>(cnt, row_off, cursor, N, E2);
    scatter_kernel<<<edgeBlocks, 256, 0, stream>>>(edge_src, edge_dst, cursor, csr_src, csr_eid, E0, E2);

    // ---- layer 1: d_in=64 -> 4 heads x 64, concat ----
    {
        dim3 g((N + 63) / 64, 4);
        gemm_tn<32><<<g, 256, 0, stream>>>(xA, W1, xB, N, 64, 256);
        attn_scores_kernel<4><<<nodeBlocks4, 256, 0, stream>>>(xB, as1, ad1, a_s, a_d, N);
        edge_scores_kernel<4><<<edgeBlocks, 256, 0, stream>>>(edge_src, edge_dst, a_s, a_d, el, E0, E2);
        aggregate_kernel<4><<<nodeBlocks4, 256, 0, stream>>>(xB, el, row_off, csr_src, csr_eid, b1, xA, N);
    }
    // ---- layer 2: 256 -> 4 heads x 64, concat ----
    {
        dim3 g((N + 63) / 64, 4);
        gemm_tn<32><<<g, 256, 0, stream>>>(xA, W2, xB, N, 256, 256);
        attn_scores_kernel<4><<<nodeBlocks4, 256, 0, stream>>>(xB, as2, ad2, a_s, a_d, N);
        edge_scores_kernel<4><<<edgeBlocks, 256, 0, stream>>>(edge_src, edge_dst, a_s, a_d, el, E0, E2);
        aggregate_kernel<4><<<nodeBlocks4, 256, 0, stream>>>(xB, el, row_off, csr_src, csr_eid, b2, xA, N);
    }
    // ---- layer 3: 256 -> 1 head x 64, mean(=identity) ----
    {
        dim3 g((N + 63) / 64, 1);
        gemm_tn<32><<<g, 256, 0, stream>>>(xA, W3, xB, N, 256, 64);
        attn_scores_kernel<1><<<nodeBlocks4, 256, 0, stream>>>(xB, as3, ad3, a_s, a_d, N);
        edge_scores_kernel<1><<<edgeBlocks, 256, 0, stream>>>(edge_src, edge_dst, a_s, a_d, el, E0, E2);
        aggregate_kernel<1><<<nodeBlocks4, 256, 0, stream>>>(xB, el, row_off, csr_src, csr_eid, b3, xA, N);
    }

    pool_kernel<<<(N + 63) / 64, 64, 0, stream>>>(xA, batch, gsums, N);
    final_kernel<<<1, ((G * 10 + 63) / 64) * 64, 0, stream>>>(gsums, gcnt, linW, linb, (float*)d_out, G);
}

// Round 2
// 894.055 us; speedup vs baseline: 1.3431x; 1.3431x over previous
//
#include <hip/hip_runtime.h>
#include <hip/hip_bf16.h>
#include <cstdint>

#define NEG_SLOPE 0.2f

// ---------------- build x = concat(emb[ids], degrees) ----------------
__global__ void build_x_kernel(const int* __restrict__ ids, const float* __restrict__ degs,
                               const float* __restrict__ emb, float* __restrict__ x, int Nn)
{
    int node = blockIdx.x * (blockDim.x >> 6) + (threadIdx.x >> 6);
    int lane = threadIdx.x & 63;
    if (node >= Nn) return;
    int id = ids[node];
    float v;
    if (lane < 62) v = emb[(size_t)id * 62 + lane];
    else           v = degs[node * 2 + (lane - 62)];
    x[(size_t)node * 64 + lane] = v;
}

// ---------------- CSR build ----------------
__global__ void hist_dst_kernel(const int* __restrict__ edst, int* __restrict__ cnt, int E0, int E2)
{
    int e = blockIdx.x * blockDim.x + threadIdx.x;
    if (e >= E2) return;
    int d = (e < E0) ? edst[e] : (e - E0);
    atomicAdd(&cnt[d], 1);
}

// graph counts from the SORTED batch array: no atomics, one wave.
__global__ void gcnt_kernel(const int* __restrict__ batch, int* __restrict__ gcnt, int Nn, int G)
{
    int g = blockIdx.x * blockDim.x + threadIdx.x;
    if (g >= G) return;
    int lo0 = 0, hi = Nn;
    while (lo0 < hi) { int mid = (lo0 + hi) >> 1; if (batch[mid] < g) lo0 = mid + 1; else hi = mid; }
    int lo1 = lo0; hi = Nn;
    while (lo1 < hi) { int mid = (lo1 + hi) >> 1; if (batch[mid] < g + 1) lo1 = mid + 1; else hi = mid; }
    gcnt[g] = lo1 - lo0;
}

__global__ void scan_kernel(const int* __restrict__ cnt, int* __restrict__ row_off,
                            int* __restrict__ cursor, int Nn, int total)
{
    __shared__ int part[1024];
    int t = threadIdx.x;
    const int CH = (Nn + 1023) / 1024;
    int base = t * CH;
    int sum = 0;
    for (int i = 0; i < CH; ++i) {
        int idx = base + i;
        if (idx < Nn) sum += cnt[idx];
    }
    part[t] = sum;
    __syncthreads();
    for (int off = 1; off < 1024; off <<= 1) {
        int v = (t >= off) ? part[t - off] : 0;
        __syncthreads();
        part[t] += v;
        __syncthreads();
    }
    int run = (t == 0) ? 0 : part[t - 1];
    for (int i = 0; i < CH; ++i) {
        int idx = base + i;
        if (idx < Nn) {
            row_off[idx] = run;
            cursor[idx] = run;
            run += cnt[idx];
        }
    }
    if (t == 1023) row_off[Nn] = total;
}

__global__ void scatter_kernel(const int* __restrict__ esrc, const int* __restrict__ edst,
                               int* __restrict__ cursor, int* __restrict__ csr_src,
                               int E0, int E2)
{
    int e = blockIdx.x * blockDim.x + threadIdx.x;
    if (e >= E2) return;
    int s, d;
    if (e < E0) { s = esrc[e]; d = edst[e]; }
    else        { s = d = e - E0; }
    int pos = atomicAdd(&cursor[d], 1);
    csr_src[pos] = s;
}

// ---------------- fp32 GEMM: H[n,f] = sum_k X[n,k] * W[f,k] ----------------
// Epilogue fuses the per-head attention dot products: each block's 64 output
// columns are exactly one head's C=64 channels, so a_s/a_d are a tx-group
// (16-lane) shfl reduction of acc * att.
template<int BK>
__global__ void gemm_tn(const float* __restrict__ X, const float* __restrict__ W,
                        float* __restrict__ Hout,
                        const float* __restrict__ aSrc, const float* __restrict__ aDst,
                        float* __restrict__ a_s, float* __restrict__ a_d,
                        int Nn, int K, int F)
{
    __shared__ float As[BK][64 + 1];
    __shared__ float Bs[BK][64 + 1];
    int bn = blockIdx.x * 64;
    int bf = blockIdx.y * 64;
    int tid = threadIdx.x;          // 256 threads
    int tx = tid & 15, ty = tid >> 4;
    float acc[4][4];
#pragma unroll
    for (int i = 0; i < 4; ++i)
#pragma unroll
        for (int j = 0; j < 4; ++j) acc[i][j] = 0.f;

    for (int k0 = 0; k0 < K; k0 += BK) {
#pragma unroll
        for (int i = 0; i < (64 * BK) / 256; ++i) {
            int idx = tid + i * 256;
            int r = idx / BK, c = idx % BK;
            int n = bn + r;
            As[c][r] = (n < Nn) ? X[(size_t)n * K + k0 + c] : 0.f;
            Bs[c][r] = W[(size_t)(bf + r) * K + k0 + c];
        }
        __syncthreads();
#pragma unroll
        for (int kk = 0; kk < BK; ++kk) {
            float a[4], b[4];
#pragma unroll
            for (int i = 0; i < 4; ++i) a[i] = As[kk][ty * 4 + i];
#pragma unroll
            for (int j = 0; j < 4; ++j) b[j] = Bs[kk][tx * 4 + j];
#pragma unroll
            for (int i = 0; i < 4; ++i)
#pragma unroll
                for (int j = 0; j < 4; ++j) acc[i][j] += a[i] * b[j];
        }
        __syncthreads();
    }
#pragma unroll
    for (int i = 0; i < 4; ++i) {
        int n = bn + ty * 4 + i;
        if (n < Nn) {
#pragma unroll
            for (int j = 0; j < 4; ++j)
                Hout[(size_t)n * F + bf + tx * 4 + j] = acc[i][j];
        }
    }

    // fused attention coefficient epilogue
    int head = bf >> 6;
    int Hh = F >> 6;
    float ps[4], pd[4];
#pragma unroll
    for (int i = 0; i < 4; ++i) { ps[i] = 0.f; pd[i] = 0.f; }
#pragma unroll
    for (int i = 0; i < 4; ++i)
#pragma unroll
        for (int j = 0; j < 4; ++j) {
            float sa = aSrc[bf + tx * 4 + j];
            float da = aDst[bf + tx * 4 + j];
            ps[i] += acc[i][j] * sa;
            pd[i] += acc[i][j] * da;
        }
#pragma unroll
    for (int off = 8; off >= 1; off >>= 1)
#pragma unroll
        for (int i = 0; i < 4; ++i) {
            ps[i] += __shfl_xor(ps[i], off, 64);
            pd[i] += __shfl_xor(pd[i], off, 64);
        }
    if (tx == 0) {
#pragma unroll
        for (int i = 0; i < 4; ++i) {
            int n = bn + ty * 4 + i;
            if (n < Nn) {
                a_s[(size_t)n * Hh + head] = ps[i];
                a_d[(size_t)n * Hh + head] = pd[i];
            }
        }
    }
}

// ---------------- per-dst-node softmax + weighted aggregation ----------------
// Edge scores are recomputed from a_s/a_d (bit-identical in all three passes).
template<int H>
__global__ void aggregate_kernel(const float* __restrict__ Hb,
                                 const float* __restrict__ a_s, const float* __restrict__ a_d,
                                 const int* __restrict__ row_off, const int* __restrict__ csr_src,
                                 const float* __restrict__ bias,
                                 float* __restrict__ out, int Nn)
{
    constexpr int F = H * 64;
    constexpr int VEC = F / 64;
    int node = blockIdx.x * (blockDim.x >> 6) + (threadIdx.x >> 6);
    int lane = threadIdx.x & 63;
    if (node >= Nn) return;
    int start = row_off[node], end = row_off[node + 1];

    float adn[H];
#pragma unroll
    for (int h = 0; h < H; ++h) adn[h] = a_d[(size_t)node * H + h];

    float m[H], s[H];
#pragma unroll
    for (int h = 0; h < H; ++h) { m[h] = -1e30f; s[h] = 0.f; }

    // pass A: per-head max over incoming edges (lane-parallel)
    for (int j = start + lane; j < end; j += 64) {
        int sn = csr_src[j];
#pragma unroll
        for (int h = 0; h < H; ++h) {
            float v = a_s[(size_t)sn * H + h] + adn[h];
            v = (v > 0.f) ? v : NEG_SLOPE * v;
            m[h] = fmaxf(m[h], v);
        }
    }
#pragma unroll
    for (int off = 32; off >= 1; off >>= 1)
#pragma unroll
        for (int h = 0; h < H; ++h) m[h] = fmaxf(m[h], __shfl_xor(m[h], off, 64));

    // pass B: sum of exp
    for (int j = start + lane; j < end; j += 64) {
        int sn = csr_src[j];
#pragma unroll
        for (int h = 0; h < H; ++h) {
            float v = a_s[(size_t)sn * H + h] + adn[h];
            v = (v > 0.f) ? v : NEG_SLOPE * v;
            s[h] += __expf(v - m[h]);
        }
    }
#pragma unroll
    for (int off = 32; off >= 1; off >>= 1)
#pragma unroll
        for (int h = 0; h < H; ++h) s[h] += __shfl_xor(s[h], off, 64);

    int head; float mh, sh, adh;
    if (H == 1) { head = 0; mh = m[0]; sh = s[0]; adh = adn[0]; }
    else {
        head = lane >> 4;
        mh  = (head == 0) ? m[0]   : (head == 1) ? m[1]   : (head == 2) ? m[2]   : m[3];
        sh  = (head == 0) ? s[0]   : (head == 1) ? s[1]   : (head == 2) ? s[2]   : s[3];
        adh = (head == 0) ? adn[0] : (head == 1) ? adn[1] : (head == 2) ? adn[2] : adn[3];
    }
    float invh = 1.f / (sh + 1e-16f);

    // pass C: weighted sum of h[src] (whole wave per edge; coalesced reads)
    float acc[VEC];
#pragma unroll
    for (int k = 0; k < VEC; ++k) acc[k] = 0.f;
    for (int j = start; j < end; ++j) {
        int sn = csr_src[j];
        float v = a_s[(size_t)sn * H + head] + adh;
        v = (v > 0.f) ? v : NEG_SLOPE * v;
        float ex = __expf(v - mh);
        const float* hp = Hb + (size_t)sn * F + lane * VEC;
#pragma unroll
        for (int k = 0; k < VEC; ++k) acc[k] += ex * hp[k];
    }
#pragma unroll
    for (int k = 0; k < VEC; ++k) {
        int f = lane * VEC + k;
        float v = acc[k] * invh + bias[f];
        out[(size_t)node * F + f] = (v > 0.f) ? v : 0.f;   // fused ReLU
    }
}

// ---------------- global mean pool (sums) ----------------
__global__ void pool_kernel(const float* __restrict__ x, const int* __restrict__ batch,
                            float* __restrict__ gsums, int Nn)
{
    int lane = threadIdx.x;        // blockDim = 64
    int n0 = blockIdx.x * 64;
    if (n0 >= Nn) return;
    int nend = min(n0 + 64, Nn);
    float acc = 0.f;
    int gcur = batch[n0];
    for (int n = n0; n < nend; ++n) {
        int g = batch[n];
        if (g != gcur) {
            atomicAdd(&gsums[gcur * 64 + lane], acc);
            acc = 0.f;
            gcur = g;
        }
        acc += x[(size_t)n * 64 + lane];
    }
    atomicAdd(&gsums[gcur * 64 + lane], acc);
}

// ---------------- final linear ----------------
__global__ void final_kernel(const float* __restrict__ gsums, const int* __restrict__ gcnt,
                             const float* __restrict__ linW, const float* __restrict__ linb,
                             float* __restrict__ out, int G)
{
    int t = threadIdx.x;
    if (t >= G * 10) return;
    int g = t / 10, j = t % 10;
    float cnt = (float)max(gcnt[g], 1);
    float acc = 0.f;
#pragma unroll
    for (int c = 0; c < 64; ++c) acc += gsums[g * 64 + c] * linW[j * 64 + c];
    out[g * 10 + j] = acc / cnt + linb[j];
}

extern "C" void kernel_launch(void* const* d_in, const int* in_sizes, int n_in,
                              void* d_out, int out_size, void* d_ws, size_t ws_size,
                              hipStream_t stream)
{
    const int*   x_ids    = (const int*)d_in[0];
    const float* degrees  = (const float*)d_in[1];
    const int*   edge_src = (const int*)d_in[2];
    const int*   edge_dst = (const int*)d_in[3];
    const int*   batch    = (const int*)d_in[4];
    const float* emb      = (const float*)d_in[5];
    const float* W1  = (const float*)d_in[6];
    const float* as1 = (const float*)d_in[7];
    const float* ad1 = (const float*)d_in[8];
    const float* b1  = (const float*)d_in[9];
    const float* W2  = (const float*)d_in[10];
    const float* as2 = (const float*)d_in[11];
    const float* ad2 = (const float*)d_in[12];
    const float* b2  = (const float*)d_in[13];
    const float* W3  = (const float*)d_in[14];
    const float* as3 = (const float*)d_in[15];
    const float* ad3 = (const float*)d_in[16];
    const float* b3  = (const float*)d_in[17];
    const float* linW = (const float*)d_in[18];
    const float* linb = (const float*)d_in[19];

    const int N  = in_sizes[0];
    const int E0 = in_sizes[2];
    const int E2 = E0 + N;
    const int G  = out_size / 10;

    char* p = (char*)d_ws;
    size_t off = 0;
    auto take = [&](size_t bytes) {
        void* q = p + off;
        off = (off + bytes + 255) & ~(size_t)255;
        return q;
    };
    float* xA      = (float*)take((size_t)N * 256 * 4);
    float* xB      = (float*)take((size_t)N * 256 * 4);
    float* a_s     = (float*)take((size_t)N * 4 * 4);
    float* a_d     = (float*)take((size_t)N * 4 * 4);
    int*   cnt     = (int*)take((size_t)N * 4);
    int*   row_off = (int*)take((size_t)(N + 1) * 4);
    int*   cursor  = (int*)take((size_t)N * 4);
    int*   csr_src = (int*)take((size_t)E2 * 4);
    float* gsums   = (float*)take((size_t)G * 64 * 4);
    int*   gcnt    = (int*)take((size_t)G * 4);

    hipMemsetAsync(cnt, 0, (size_t)N * 4, stream);
    hipMemsetAsync(gsums, 0, (size_t)G * 64 * 4, stream);

    const int nodeBlocks4 = (N + 3) / 4;          // 4 waves (nodes) per 256-thread block
    const int edgeBlocks  = (E2 + 255) / 256;

    build_x_kernel<<<nodeBlocks4, 256, 0, stream>>>(x_ids, degrees, emb, xA, N);
    hist_dst_kernel<<<edgeBlocks, 256, 0, stream>>>(edge_dst, cnt, E0, E2);
    gcnt_kernel<<<1, 64, 0, stream>>>(batch, gcnt, N, G);
    scan_kernel<<<1, 1024, 0, stream>>>(cnt, row_off, cursor, N, E2);
    scatter_kernel<<<edgeBlocks, 256, 0, stream>>>(edge_src, edge_dst, cursor, csr_src, E0, E2);

    // ---- layer 1: d_in=64 -> 4 heads x 64, concat ----
    {
        dim3 g((N + 63) / 64, 4);
        gemm_tn<32><<<g, 256, 0, stream>>>(xA, W1, xB, as1, ad1, a_s, a_d, N, 64, 256);
        aggregate_kernel<4><<<nodeBlocks4, 256, 0, stream>>>(xB, a_s, a_d, row_off, csr_src, b1, xA, N);
    }
    // ---- layer 2: 256 -> 4 heads x 64, concat ----
    {
        dim3 g((N + 63) / 64, 4);
        gemm_tn<32><<<g, 256, 0, stream>>>(xA, W2, xB, as2, ad2, a_s, a_d, N, 256, 256);
        aggregate_kernel<4><<<nodeBlocks4, 256, 0, stream>>>(xB, a_s, a_d, row_off, csr_src, b2, xA, N);
    }
    // ---- layer 3: 256 -> 1 head x 64, mean(=identity) ----
    {
        dim3 g((N + 63) / 64, 1);
        gemm_tn<32><<<g, 256, 0, stream>>>(xA, W3, xB, as3, ad3, a_s, a_d, N, 256, 64);
        aggregate_kernel<1><<<nodeBlocks4, 256, 0, stream>>>(xB, a_s, a_d, row_off, csr_src, b3, xA, N);
    }

    pool_kernel<<<(N + 63) / 64, 64, 0, stream>>>(xA, batch, gsums, N);
    final_kernel<<<1, ((G * 10 + 63) / 64) * 64, 0, stream>>>(gsums, gcnt, linW, linb, (float*)d_out, G);
}

// Round 3
// 589.482 us; speedup vs baseline: 2.0371x; 1.5167x over previous
//
#include <hip/hip_runtime.h>
#include <hip/hip_bf16.h>
#include <cstdint>

#define NEG_SLOPE 0.2f

typedef __bf16 bf16x8 __attribute__((ext_vector_type(8)));
typedef float  f32x4  __attribute__((ext_vector_type(4)));

__device__ __forceinline__ unsigned short f2bf(float f) {
    unsigned int u = __float_as_uint(f);
    u += 0x7fffu + ((u >> 16) & 1u);          // round-to-nearest-even
    return (unsigned short)(u >> 16);
}
__device__ __forceinline__ float bf2f(unsigned short u) {
    return __uint_as_float((unsigned int)u << 16);
}

// ---------------- fp32 -> bf16 weight conversion ----------------
__global__ void f2bf_kernel(const float* __restrict__ in, unsigned short* __restrict__ out, int n)
{
    int i = blockIdx.x * blockDim.x + threadIdx.x;
    if (i < n) out[i] = f2bf(in[i]);
}

// ---------------- build x = concat(emb[ids], degrees) (bf16) ----------------
__global__ void build_x_kernel(const int* __restrict__ ids, const float* __restrict__ degs,
                               const float* __restrict__ emb, unsigned short* __restrict__ x, int Nn)
{
    int node = blockIdx.x * (blockDim.x >> 6) + (threadIdx.x >> 6);
    int lane = threadIdx.x & 63;
    if (node >= Nn) return;
    int id = ids[node];
    float v;
    if (lane < 62) v = emb[(size_t)id * 62 + lane];
    else           v = degs[node * 2 + (lane - 62)];
    x[(size_t)node * 64 + lane] = f2bf(v);
}

// ---------------- CSR build ----------------
__global__ void hist_dst_kernel(const int* __restrict__ edst, int* __restrict__ cnt, int E0, int E2)
{
    int e = blockIdx.x * blockDim.x + threadIdx.x;
    if (e >= E2) return;
    int d = (e < E0) ? edst[e] : (e - E0);
    atomicAdd(&cnt[d], 1);
}

__global__ void gcnt_kernel(const int* __restrict__ batch, int* __restrict__ gcnt, int Nn, int G)
{
    int g = blockIdx.x * blockDim.x + threadIdx.x;
    if (g >= G) return;
    int lo0 = 0, hi = Nn;
    while (lo0 < hi) { int mid = (lo0 + hi) >> 1; if (batch[mid] < g) lo0 = mid + 1; else hi = mid; }
    int lo1 = lo0; hi = Nn;
    while (lo1 < hi) { int mid = (lo1 + hi) >> 1; if (batch[mid] < g + 1) lo1 = mid + 1; else hi = mid; }
    gcnt[g] = lo1 - lo0;
}

__global__ void scan_kernel(const int* __restrict__ cnt, int* __restrict__ row_off,
                            int* __restrict__ cursor, int Nn, int total)
{
    __shared__ int part[1024];
    int t = threadIdx.x;
    const int CH = (Nn + 1023) / 1024;
    int base = t * CH;
    int sum = 0;
    for (int i = 0; i < CH; ++i) {
        int idx = base + i;
        if (idx < Nn) sum += cnt[idx];
    }
    part[t] = sum;
    __syncthreads();
    for (int off = 1; off < 1024; off <<= 1) {
        int v = (t >= off) ? part[t - off] : 0;
        __syncthreads();
        part[t] += v;
        __syncthreads();
    }
    int run = (t == 0) ? 0 : part[t - 1];
    for (int i = 0; i < CH; ++i) {
        int idx = base + i;
        if (idx < Nn) {
            row_off[idx] = run;
            cursor[idx] = run;
            run += cnt[idx];
        }
    }
    if (t == 1023) row_off[Nn] = total;
}

__global__ void scatter_kernel(const int* __restrict__ esrc, const int* __restrict__ edst,
                               int* __restrict__ cursor, int* __restrict__ csr_src,
                               int E0, int E2)
{
    int e = blockIdx.x * blockDim.x + threadIdx.x;
    if (e >= E2) return;
    int s, d;
    if (e < E0) { s = esrc[e]; d = edst[e]; }
    else        { s = d = e - E0; }
    int pos = atomicAdd(&cursor[d], 1);
    csr_src[pos] = s;
}

// ---------------- bf16 MFMA GEMM: H[n,f] = sum_k X[n,k]*W[f,k] ----------------
// One wave per 16(M) x 64(F) tile. A/B frags loaded directly (contiguous-K slots;
// identical slot order on A and B makes the k-permutation harmless).
// Fused epilogue: a_s/a_d attention dot products from the fp32 accumulators.
__global__ void gemm_mfma(const unsigned short* __restrict__ X, const unsigned short* __restrict__ Wb,
                          unsigned short* __restrict__ Hout,
                          const float* __restrict__ aSrc, const float* __restrict__ aDst,
                          float* __restrict__ a_s, float* __restrict__ a_d,
                          int Nn, int K, int F)
{
    int wid  = (blockIdx.x * blockDim.x + threadIdx.x) >> 6;
    int lane = threadIdx.x & 63;
    int mtiles = (Nn + 15) >> 4;
    int ftiles = F >> 6;
    if (wid >= mtiles * ftiles) return;
    int ft = wid / mtiles;
    int mt = wid - ft * mtiles;
    int m0 = mt << 4, f0 = ft << 6;
    int r = lane & 15, g = lane >> 4;
    int g4 = g << 2;

    int arow_i = m0 + r; if (arow_i >= Nn) arow_i = Nn - 1;   // clamp (Nn%16==0 in practice)
    const unsigned short* xrow = X + (size_t)arow_i * K + g * 8;
    const unsigned short* wrow = Wb + (size_t)(f0 + r) * K + g * 8;
    const size_t wstep = (size_t)16 * K;

    f32x4 acc[4];
#pragma unroll
    for (int j = 0; j < 4; ++j) acc[j] = f32x4{0.f, 0.f, 0.f, 0.f};

    for (int k0 = 0; k0 < K; k0 += 32) {
        bf16x8 av = *reinterpret_cast<const bf16x8*>(xrow + k0);
#pragma unroll
        for (int j = 0; j < 4; ++j) {
            bf16x8 bv = *reinterpret_cast<const bf16x8*>(wrow + j * wstep + k0);
            acc[j] = __builtin_amdgcn_mfma_f32_16x16x32_bf16(av, bv, acc[j], 0, 0, 0);
        }
    }

    // store H (bf16). C/D layout: col = lane&15, row = (lane>>4)*4 + reg.
#pragma unroll
    for (int j = 0; j < 4; ++j) {
#pragma unroll
        for (int q = 0; q < 4; ++q) {
            int row = m0 + g4 + q;
            if (row < Nn)
                Hout[(size_t)row * F + f0 + j * 16 + r] = f2bf(acc[j][q]);
        }
    }

    // fused attention-coefficient epilogue (fp32)
    float ps[4] = {0.f, 0.f, 0.f, 0.f};
    float pd[4] = {0.f, 0.f, 0.f, 0.f};
#pragma unroll
    for (int j = 0; j < 4; ++j) {
        float ws_ = aSrc[f0 + j * 16 + r];
        float wd_ = aDst[f0 + j * 16 + r];
#pragma unroll
        for (int q = 0; q < 4; ++q) {
            ps[q] += acc[j][q] * ws_;
            pd[q] += acc[j][q] * wd_;
        }
    }
#pragma unroll
    for (int off = 1; off < 16; off <<= 1)
#pragma unroll
        for (int q = 0; q < 4; ++q) {
            ps[q] += __shfl_xor(ps[q], off, 64);
            pd[q] += __shfl_xor(pd[q], off, 64);
        }
    if (r == 0) {
        int Hh = F >> 6;
#pragma unroll
        for (int q = 0; q < 4; ++q) {
            int n = m0 + g4 + q;
            if (n < Nn) {
                a_s[(size_t)n * Hh + ft] = ps[q];
                a_d[(size_t)n * Hh + ft] = pd[q];
            }
        }
    }
}

// ---------------- softmax + weighted aggregation (bf16 H, fp32 scores) ----------------
template<int H>
__global__ void aggregate_kernel(const unsigned short* __restrict__ Hb,
                                 const float* __restrict__ a_s, const float* __restrict__ a_d,
                                 const int* __restrict__ row_off, const int* __restrict__ csr_src,
                                 const float* __restrict__ bias,
                                 unsigned short* __restrict__ out, int Nn)
{
    constexpr int F = H * 64;
    constexpr int VEC = F / 64;
    int node = blockIdx.x * (blockDim.x >> 6) + (threadIdx.x >> 6);
    int lane = threadIdx.x & 63;
    if (node >= Nn) return;
    int start = row_off[node], end = row_off[node + 1];
    int deg = end - start;

    float adn[H];
#pragma unroll
    for (int h = 0; h < H; ++h) adn[h] = a_d[(size_t)node * H + h];

    int head = (H == 1) ? 0 : (lane >> 4);

    if (deg <= 64) {
        // -------- fast path: whole neighborhood in lane registers --------
        bool act = lane < deg;
        int sn = act ? csr_src[start + lane] : 0;
        float v[H];
        if (H == 4) {
            const f32x4 av = *reinterpret_cast<const f32x4*>(a_s + (size_t)sn * 4);
#pragma unroll
            for (int h = 0; h < 4; ++h) {
                float t = av[h] + adn[h];
                t = (t > 0.f) ? t : NEG_SLOPE * t;
                v[h] = act ? t : -1e30f;
            }
        } else {
            float t = a_s[sn] + adn[0];
            t = (t > 0.f) ? t : NEG_SLOPE * t;
            v[0] = act ? t : -1e30f;
        }
        float m[H];
#pragma unroll
        for (int h = 0; h < H; ++h) {
            m[h] = v[h];
#pragma unroll
            for (int off = 32; off >= 1; off >>= 1)
                m[h] = fmaxf(m[h], __shfl_xor(m[h], off, 64));
        }
        float e[H], s[H];
#pragma unroll
        for (int h = 0; h < H; ++h) {
            e[h] = act ? __expf(v[h] - m[h]) : 0.f;
            s[h] = e[h];
#pragma unroll
            for (int off = 32; off >= 1; off >>= 1)
                s[h] += __shfl_xor(s[h], off, 64);
        }
        float sh;
        if (H == 1) sh = s[0];
        else sh = (head == 0) ? s[0] : (head == 1) ? s[1] : (head == 2) ? s[2] : s[3];
        float inv = 1.f / (sh + 1e-16f);

        float acc[VEC];
#pragma unroll
        for (int k = 0; k < VEC; ++k) acc[k] = 0.f;

        unsigned int eb0 = __float_as_uint(e[0]);
        unsigned int eb1 = (H == 4) ? __float_as_uint(e[1]) : 0u;
        unsigned int eb2 = (H == 4) ? __float_as_uint(e[2]) : 0u;
        unsigned int eb3 = (H == 4) ? __float_as_uint(e[3]) : 0u;

        for (int j = 0; j < deg; ++j) {
            int snj = __builtin_amdgcn_readlane(sn, j);
            float exj;
            if (H == 1) {
                exj = __uint_as_float(__builtin_amdgcn_readlane(eb0, j));
            } else {
                unsigned int w0 = __builtin_amdgcn_readlane(eb0, j);
                unsigned int w1 = __builtin_amdgcn_readlane(eb1, j);
                unsigned int w2 = __builtin_amdgcn_readlane(eb2, j);
                unsigned int w3 = __builtin_amdgcn_readlane(eb3, j);
                unsigned int ws_ = (head < 2) ? ((head == 0) ? w0 : w1)
                                              : ((head == 2) ? w2 : w3);
                exj = __uint_as_float(ws_);
            }
            if (H == 4) {
                const ushort4 u = *reinterpret_cast<const ushort4*>(Hb + (size_t)snj * 256 + lane * 4);
                acc[0] += exj * bf2f(u.x);
                acc[1] += exj * bf2f(u.y);
                acc[2] += exj * bf2f(u.z);
                acc[3] += exj * bf2f(u.w);
            } else {
                acc[0] += exj * bf2f(Hb[(size_t)snj * 64 + lane]);
            }
        }

        if (H == 4) {
            ushort4 o;
            float t0 = acc[0] * inv + bias[lane * 4 + 0]; o.x = f2bf(t0 > 0.f ? t0 : 0.f);
            float t1 = acc[1] * inv + bias[lane * 4 + 1]; o.y = f2bf(t1 > 0.f ? t1 : 0.f);
            float t2 = acc[2] * inv + bias[lane * 4 + 2]; o.z = f2bf(t2 > 0.f ? t2 : 0.f);
            float t3 = acc[3] * inv + bias[lane * 4 + 3]; o.w = f2bf(t3 > 0.f ? t3 : 0.f);
            *reinterpret_cast<ushort4*>(out + (size_t)node * 256 + lane * 4) = o;
        } else {
            float t = acc[0] * inv + bias[lane];
            out[(size_t)node * 64 + lane] = f2bf(t > 0.f ? t : 0.f);
        }
        return;
    }

    // -------- slow path (deg > 64): generic two-pass --------
    float m[H], s[H];
#pragma unroll
    for (int h = 0; h < H; ++h) { m[h] = -1e30f; s[h] = 0.f; }
    for (int j = start + lane; j < end; j += 64) {
        int sn = csr_src[j];
#pragma unroll
        for (int h = 0; h < H; ++h) {
            float t = a_s[(size_t)sn * H + h] + adn[h];
            t = (t > 0.f) ? t : NEG_SLOPE * t;
            m[h] = fmaxf(m[h], t);
        }
    }
#pragma unroll
    for (int off = 32; off >= 1; off >>= 1)
#pragma unroll
        for (int h = 0; h < H; ++h) m[h] = fmaxf(m[h], __shfl_xor(m[h], off, 64));
    for (int j = start + lane; j < end; j += 64) {
        int sn = csr_src[j];
#pragma unroll
        for (int h = 0; h < H; ++h) {
            float t = a_s[(size_t)sn * H + h] + adn[h];
            t = (t > 0.f) ? t : NEG_SLOPE * t;
            s[h] += __expf(t - m[h]);
        }
    }
#pragma unroll
    for (int off = 32; off >= 1; off >>= 1)
#pragma unroll
        for (int h = 0; h < H; ++h) s[h] += __shfl_xor(s[h], off, 64);

    float mh, sh, adh;
    if (H == 1) { mh = m[0]; sh = s[0]; adh = adn[0]; }
    else {
        mh  = (head == 0) ? m[0]   : (head == 1) ? m[1]   : (head == 2) ? m[2]   : m[3];
        sh  = (head == 0) ? s[0]   : (head == 1) ? s[1]   : (head == 2) ? s[2]   : s[3];
        adh = (head == 0) ? adn[0] : (head == 1) ? adn[1] : (head == 2) ? adn[2] : adn[3];
    }
    float inv = 1.f / (sh + 1e-16f);
    float acc[VEC];
#pragma unroll
    for (int k = 0; k < VEC; ++k) acc[k] = 0.f;
    for (int j = start; j < end; ++j) {
        int sn = csr_src[j];
        float t = a_s[(size_t)sn * H + head] + adh;
        t = (t > 0.f) ? t : NEG_SLOPE * t;
        float ex = __expf(t - mh);
        const unsigned short* hp = Hb + (size_t)sn * F + lane * VEC;
#pragma unroll
        for (int k = 0; k < VEC; ++k) acc[k] += ex * bf2f(hp[k]);
    }
#pragma unroll
    for (int k = 0; k < VEC; ++k) {
        int f = lane * VEC + k;
        float t = acc[k] * inv + bias[f];
        out[(size_t)node * F + f] = f2bf(t > 0.f ? t : 0.f);
    }
}

// ---------------- global mean pool (sums, bf16 input) ----------------
__global__ void pool_kernel(const unsigned short* __restrict__ x, const int* __restrict__ batch,
                            float* __restrict__ gsums, int Nn)
{
    int lane = threadIdx.x;        // blockDim = 64
    int n0 = blockIdx.x * 64;
    if (n0 >= Nn) return;
    int nend = min(n0 + 64, Nn);
    float acc = 0.f;
    int gcur = batch[n0];
    for (int n = n0; n < nend; ++n) {
        int g = batch[n];
        if (g != gcur) {
            atomicAdd(&gsums[gcur * 64 + lane], acc);
            acc = 0.f;
            gcur = g;
        }
        acc += bf2f(x[(size_t)n * 64 + lane]);
    }
    atomicAdd(&gsums[gcur * 64 + lane], acc);
}

// ---------------- final linear ----------------
__global__ void final_kernel(const float* __restrict__ gsums, const int* __restrict__ gcnt,
                             const float* __restrict__ linW, const float* __restrict__ linb,
                             float* __restrict__ out, int G)
{
    int t = threadIdx.x;
    if (t >= G * 10) return;
    int g = t / 10, j = t % 10;
    float cnt = (float)max(gcnt[g], 1);
    float acc = 0.f;
#pragma unroll
    for (int c = 0; c < 64; ++c) acc += gsums[g * 64 + c] * linW[j * 64 + c];
    out[g * 10 + j] = acc / cnt + linb[j];
}

extern "C" void kernel_launch(void* const* d_in, const int* in_sizes, int n_in,
                              void* d_out, int out_size, void* d_ws, size_t ws_size,
                              hipStream_t stream)
{
    const int*   x_ids    = (const int*)d_in[0];
    const float* degrees  = (const float*)d_in[1];
    const int*   edge_src = (const int*)d_in[2];
    const int*   edge_dst = (const int*)d_in[3];
    const int*   batch    = (const int*)d_in[4];
    const float* emb      = (const float*)d_in[5];
    const float* W1  = (const float*)d_in[6];
    const float* as1 = (const float*)d_in[7];
    const float* ad1 = (const float*)d_in[8];
    const float* b1  = (const float*)d_in[9];
    const float* W2  = (const float*)d_in[10];
    const float* as2 = (const float*)d_in[11];
    const float* ad2 = (const float*)d_in[12];
    const float* b2  = (const float*)d_in[13];
    const float* W3  = (const float*)d_in[14];
    const float* as3 = (const float*)d_in[15];
    const float* ad3 = (const float*)d_in[16];
    const float* b3  = (const float*)d_in[17];
    const float* linW = (const float*)d_in[18];
    const float* linb = (const float*)d_in[19];

    const int N  = in_sizes[0];
    const int E0 = in_sizes[2];
    const int E2 = E0 + N;
    const int G  = out_size / 10;
    const int nW1 = in_sizes[6], nW2 = in_sizes[10], nW3 = in_sizes[14];

    char* p = (char*)d_ws;
    size_t off = 0;
    auto take = [&](size_t bytes) {
        void* q = p + off;
        off = (off + bytes + 255) & ~(size_t)255;
        return q;
    };
    unsigned short* xA  = (unsigned short*)take((size_t)N * 256 * 2);
    unsigned short* xB  = (unsigned short*)take((size_t)N * 256 * 2);
    float* a_s     = (float*)take((size_t)N * 4 * 4);
    float* a_d     = (float*)take((size_t)N * 4 * 4);
    int*   cnt     = (int*)take((size_t)N * 4);
    int*   row_off = (int*)take((size_t)(N + 1) * 4);
    int*   cursor  = (int*)take((size_t)N * 4);
    int*   csr_src = (int*)take((size_t)E2 * 4);
    float* gsums   = (float*)take((size_t)G * 64 * 4);
    int*   gcnt    = (int*)take((size_t)G * 4);
    unsigned short* w1b = (unsigned short*)take((size_t)nW1 * 2);
    unsigned short* w2b = (unsigned short*)take((size_t)nW2 * 2);
    unsigned short* w3b = (unsigned short*)take((size_t)nW3 * 2);

    hipMemsetAsync(cnt, 0, (size_t)N * 4, stream);
    hipMemsetAsync(gsums, 0, (size_t)G * 64 * 4, stream);

    const int nodeBlocks4 = (N + 3) / 4;
    const int edgeBlocks  = (E2 + 255) / 256;

    f2bf_kernel<<<(nW1 + 255) / 256, 256, 0, stream>>>(W1, w1b, nW1);
    f2bf_kernel<<<(nW2 + 255) / 256, 256, 0, stream>>>(W2, w2b, nW2);
    f2bf_kernel<<<(nW3 + 255) / 256, 256, 0, stream>>>(W3, w3b, nW3);

    build_x_kernel<<<nodeBlocks4, 256, 0, stream>>>(x_ids, degrees, emb, xA, N);
    hist_dst_kernel<<<edgeBlocks, 256, 0, stream>>>(edge_dst, cnt, E0, E2);
    gcnt_kernel<<<1, 64, 0, stream>>>(batch, gcnt, N, G);
    scan_kernel<<<1, 1024, 0, stream>>>(cnt, row_off, cursor, N, E2);
    scatter_kernel<<<edgeBlocks, 256, 0, stream>>>(edge_src, edge_dst, cursor, csr_src, E0, E2);

    const int mtiles = (N + 15) / 16;
    auto gemmBlocks = [&](int ftiles) { return (mtiles * ftiles + 3) / 4; };

    // ---- layer 1: 64 -> 4x64 concat ----
    gemm_mfma<<<gemmBlocks(4), 256, 0, stream>>>(xA, w1b, xB, as1, ad1, a_s, a_d, N, 64, 256);
    aggregate_kernel<4><<<nodeBlocks4, 256, 0, stream>>>(xB, a_s, a_d, row_off, csr_src, b1, xA, N);
    // ---- layer 2: 256 -> 4x64 concat ----
    gemm_mfma<<<gemmBlocks(4), 256, 0, stream>>>(xA, w2b, xB, as2, ad2, a_s, a_d, N, 256, 256);
    aggregate_kernel<4><<<nodeBlocks4, 256, 0, stream>>>(xB, a_s, a_d, row_off, csr_src, b2, xA, N);
    // ---- layer 3: 256 -> 1x64 (mean == identity) ----
    gemm_mfma<<<gemmBlocks(1), 256, 0, stream>>>(xA, w3b, xB, as3, ad3, a_s, a_d, N, 256, 64);
    aggregate_kernel<1><<<nodeBlocks4, 256, 0, stream>>>(xB, a_s, a_d, row_off, csr_src, b3, xA, N);

    pool_kernel<<<(N + 63) / 64, 64, 0, stream>>>(xA, batch, gsums, N);
    final_kernel<<<1, ((G * 10 + 63) / 64) * 64, 0, stream>>>(gsums, gcnt, linW, linb, (float*)d_out, G);
}

// Round 4
// 473.585 us; speedup vs baseline: 2.5356x; 1.2447x over previous
//
#include <hip/hip_runtime.h>
#include <hip/hip_bf16.h>
#include <cstdint>

#define NEG_SLOPE 0.2f

typedef __bf16 bf16x8 __attribute__((ext_vector_type(8)));
typedef float  f32x4  __attribute__((ext_vector_type(4)));

__device__ __forceinline__ unsigned short f2bf(float f) {
    unsigned int u = __float_as_uint(f);
    u += 0x7fffu + ((u >> 16) & 1u);          // round-to-nearest-even
    return (unsigned short)(u >> 16);
}
__device__ __forceinline__ float bf2f(unsigned short u) {
    return __uint_as_float((unsigned int)u << 16);
}

// ---------------- fp32 -> bf16 weight conversion ----------------
__global__ void f2bf_kernel(const float* __restrict__ in, unsigned short* __restrict__ out, int n)
{
    int i = blockIdx.x * blockDim.x + threadIdx.x;
    if (i < n) out[i] = f2bf(in[i]);
}

// ---------------- build x = concat(emb[ids], degrees) (bf16) ----------------
__global__ void build_x_kernel(const int* __restrict__ ids, const float* __restrict__ degs,
                               const float* __restrict__ emb, unsigned short* __restrict__ x, int Nn)
{
    int node = blockIdx.x * (blockDim.x >> 6) + (threadIdx.x >> 6);
    int lane = threadIdx.x & 63;
    if (node >= Nn) return;
    int id = ids[node];
    float v;
    if (lane < 62) v = emb[(size_t)id * 62 + lane];
    else           v = degs[node * 2 + (lane - 62)];
    x[(size_t)node * 64 + lane] = f2bf(v);
}

// ---------------- CSR build ----------------
__global__ void hist_dst_kernel(const int* __restrict__ edst, int* __restrict__ cnt, int E0, int E2)
{
    int e = blockIdx.x * blockDim.x + threadIdx.x;
    if (e >= E2) return;
    int d = (e < E0) ? edst[e] : (e - E0);
    atomicAdd(&cnt[d], 1);
}

__global__ void gcnt_kernel(const int* __restrict__ batch, int* __restrict__ gcnt, int Nn, int G)
{
    int g = blockIdx.x * blockDim.x + threadIdx.x;
    if (g >= G) return;
    int lo0 = 0, hi = Nn;
    while (lo0 < hi) { int mid = (lo0 + hi) >> 1; if (batch[mid] < g) lo0 = mid + 1; else hi = mid; }
    int lo1 = lo0; hi = Nn;
    while (lo1 < hi) { int mid = (lo1 + hi) >> 1; if (batch[mid] < g + 1) lo1 = mid + 1; else hi = mid; }
    gcnt[g] = lo1 - lo0;
}

// ---------------- hierarchical exclusive scan (3 kernels) ----------------
// S1: per-block (2048-elem) sums
__global__ void scan_part_kernel(const int* __restrict__ cnt, int* __restrict__ part, int Nn)
{
    int t = threadIdx.x;                   // 256 threads
    int base = blockIdx.x * 2048 + t * 8;
    int s = 0;
    if (base + 8 <= Nn) {
        int4 a = *reinterpret_cast<const int4*>(cnt + base);
        int4 b = *reinterpret_cast<const int4*>(cnt + base + 4);
        s = a.x + a.y + a.z + a.w + b.x + b.y + b.z + b.w;
    } else {
        for (int k = 0; k < 8; ++k)
            if (base + k < Nn) s += cnt[base + k];
    }
#pragma unroll
    for (int off = 32; off >= 1; off >>= 1) s += __shfl_xor(s, off, 64);
    __shared__ int ws[4];
    int wid = t >> 6;
    if ((t & 63) == 0) ws[wid] = s;
    __syncthreads();
    if (t == 0) part[blockIdx.x] = ws[0] + ws[1] + ws[2] + ws[3];
}

// S2: exclusive scan of block sums (single wave; nparts <= 64)
__global__ void scan_top_kernel(int* __restrict__ part, int nparts)
{
    int t = threadIdx.x;                   // 64 threads
    int v = (t < nparts) ? part[t] : 0;
    int orig = v;
#pragma unroll
    for (int off = 1; off <= 32; off <<= 1) {
        int u = __shfl_up(v, off, 64);
        if (t >= off) v += u;
    }
    if (t < nparts) part[t] = v - orig;    // exclusive
}

// S3: per-block local exclusive prefix + block base -> row_off, cursor
__global__ void scan_down_kernel(const int* __restrict__ cnt, const int* __restrict__ part,
                                 int* __restrict__ row_off, int* __restrict__ cursor,
                                 int Nn, int total)
{
    int t = threadIdx.x;                   // 256 threads
    int base = blockIdx.x * 2048 + t * 8;
    int v[8];
    if (base + 8 <= Nn) {
        int4 a = *reinterpret_cast<const int4*>(cnt + base);
        int4 b = *reinterpret_cast<const int4*>(cnt + base + 4);
        v[0]=a.x; v[1]=a.y; v[2]=a.z; v[3]=a.w; v[4]=b.x; v[5]=b.y; v[6]=b.z; v[7]=b.w;
    } else {
#pragma unroll
        for (int k = 0; k < 8; ++k) v[k] = (base + k < Nn) ? cnt[base + k] : 0;
    }
    int tsum = 0;
#pragma unroll
    for (int k = 0; k < 8; ++k) tsum += v[k];
    int incl = tsum;
#pragma unroll
    for (int off = 1; off <= 32; off <<= 1) {
        int u = __shfl_up(incl, off, 64);
        if ((t & 63) >= off) incl += u;
    }
    int texcl = incl - tsum;
    __shared__ int ws[4];
    int wid = t >> 6;
    if ((t & 63) == 63) ws[wid] = incl;
    __syncthreads();
    int wbase = 0;
#pragma unroll
    for (int w = 0; w < 4; ++w) wbase += (w < wid) ? ws[w] : 0;
    int run = part[blockIdx.x] + wbase + texcl;

    if (base + 8 <= Nn) {
        int o[8];
#pragma unroll
        for (int k = 0; k < 8; ++k) { o[k] = run; run += v[k]; }
        *reinterpret_cast<int4*>(row_off + base)     = make_int4(o[0], o[1], o[2], o[3]);
        *reinterpret_cast<int4*>(row_off + base + 4) = make_int4(o[4], o[5], o[6], o[7]);
        *reinterpret_cast<int4*>(cursor + base)      = make_int4(o[0], o[1], o[2], o[3]);
        *reinterpret_cast<int4*>(cursor + base + 4)  = make_int4(o[4], o[5], o[6], o[7]);
    } else {
#pragma unroll
        for (int k = 0; k < 8; ++k) {
            if (base + k < Nn) {
                row_off[base + k] = run;
                cursor[base + k]  = run;
                run += v[k];
            }
        }
    }
    if (blockIdx.x == 0 && t == 0) row_off[Nn] = total;
}

__global__ void scatter_kernel(const int* __restrict__ esrc, const int* __restrict__ edst,
                               int* __restrict__ cursor, int* __restrict__ csr_src,
                               int E0, int E2)
{
    int e = blockIdx.x * blockDim.x + threadIdx.x;
    if (e >= E2) return;
    int s, d;
    if (e < E0) { s = esrc[e]; d = edst[e]; }
    else        { s = d = e - E0; }
    int pos = atomicAdd(&cursor[d], 1);
    csr_src[pos] = s;
}

// ---------------- bf16 MFMA GEMM: H[n,f] = sum_k X[n,k]*W[f,k] ----------------
__global__ void gemm_mfma(const unsigned short* __restrict__ X, const unsigned short* __restrict__ Wb,
                          unsigned short* __restrict__ Hout,
                          const float* __restrict__ aSrc, const float* __restrict__ aDst,
                          float* __restrict__ a_s, float* __restrict__ a_d,
                          int Nn, int K, int F)
{
    int wid  = (blockIdx.x * blockDim.x + threadIdx.x) >> 6;
    int lane = threadIdx.x & 63;
    int mtiles = (Nn + 15) >> 4;
    int ftiles = F >> 6;
    if (wid >= mtiles * ftiles) return;
    int ft = wid / mtiles;
    int mt = wid - ft * mtiles;
    int m0 = mt << 4, f0 = ft << 6;
    int r = lane & 15, g = lane >> 4;
    int g4 = g << 2;

    int arow_i = m0 + r; if (arow_i >= Nn) arow_i = Nn - 1;
    const unsigned short* xrow = X + (size_t)arow_i * K + g * 8;
    const unsigned short* wrow = Wb + (size_t)(f0 + r) * K + g * 8;
    const size_t wstep = (size_t)16 * K;

    f32x4 acc[4];
#pragma unroll
    for (int j = 0; j < 4; ++j) acc[j] = f32x4{0.f, 0.f, 0.f, 0.f};

    for (int k0 = 0; k0 < K; k0 += 32) {
        bf16x8 av = *reinterpret_cast<const bf16x8*>(xrow + k0);
#pragma unroll
        for (int j = 0; j < 4; ++j) {
            bf16x8 bv = *reinterpret_cast<const bf16x8*>(wrow + j * wstep + k0);
            acc[j] = __builtin_amdgcn_mfma_f32_16x16x32_bf16(av, bv, acc[j], 0, 0, 0);
        }
    }

    // store H (bf16). C/D layout: col = lane&15, row = (lane>>4)*4 + reg.
#pragma unroll
    for (int j = 0; j < 4; ++j) {
#pragma unroll
        for (int q = 0; q < 4; ++q) {
            int row = m0 + g4 + q;
            if (row < Nn)
                Hout[(size_t)row * F + f0 + j * 16 + r] = f2bf(acc[j][q]);
        }
    }

    // fused attention-coefficient epilogue (fp32)
    float ps[4] = {0.f, 0.f, 0.f, 0.f};
    float pd[4] = {0.f, 0.f, 0.f, 0.f};
#pragma unroll
    for (int j = 0; j < 4; ++j) {
        float ws_ = aSrc[f0 + j * 16 + r];
        float wd_ = aDst[f0 + j * 16 + r];
#pragma unroll
        for (int q = 0; q < 4; ++q) {
            ps[q] += acc[j][q] * ws_;
            pd[q] += acc[j][q] * wd_;
        }
    }
#pragma unroll
    for (int off = 1; off < 16; off <<= 1)
#pragma unroll
        for (int q = 0; q < 4; ++q) {
            ps[q] += __shfl_xor(ps[q], off, 64);
            pd[q] += __shfl_xor(pd[q], off, 64);
        }
    if (r == 0) {
        int Hh = F >> 6;
#pragma unroll
        for (int q = 0; q < 4; ++q) {
            int n = m0 + g4 + q;
            if (n < Nn) {
                a_s[(size_t)n * Hh + ft] = ps[q];
                a_d[(size_t)n * Hh + ft] = pd[q];
            }
        }
    }
}

// ---------------- softmax + weighted aggregation (bf16 H, fp32 scores) ----------------
template<int H>
__global__ void aggregate_kernel(const unsigned short* __restrict__ Hb,
                                 const float* __restrict__ a_s, const float* __restrict__ a_d,
                                 const int* __restrict__ row_off, const int* __restrict__ csr_src,
                                 const float* __restrict__ bias,
                                 unsigned short* __restrict__ out, int Nn)
{
    constexpr int F = H * 64;
    constexpr int VEC = F / 64;
    int node = blockIdx.x * (blockDim.x >> 6) + (threadIdx.x >> 6);
    int lane = threadIdx.x & 63;
    if (node >= Nn) return;
    int start = row_off[node], end = row_off[node + 1];
    int deg = end - start;

    float adn[H];
#pragma unroll
    for (int h = 0; h < H; ++h) adn[h] = a_d[(size_t)node * H + h];

    int head = (H == 1) ? 0 : (lane >> 4);

    if (deg <= 64) {
        bool act = lane < deg;
        int sn = act ? csr_src[start + lane] : 0;
        float v[H];
        if (H == 4) {
            const f32x4 av = *reinterpret_cast<const f32x4*>(a_s + (size_t)sn * 4);
#pragma unroll
            for (int h = 0; h < 4; ++h) {
                float t = av[h] + adn[h];
                t = (t > 0.f) ? t : NEG_SLOPE * t;
                v[h] = act ? t : -1e30f;
            }
        } else {
            float t = a_s[sn] + adn[0];
            t = (t > 0.f) ? t : NEG_SLOPE * t;
            v[0] = act ? t : -1e30f;
        }
        float m[H];
#pragma unroll
        for (int h = 0; h < H; ++h) {
            m[h] = v[h];
#pragma unroll
            for (int off = 32; off >= 1; off >>= 1)
                m[h] = fmaxf(m[h], __shfl_xor(m[h], off, 64));
        }
        float e[H], s[H];
#pragma unroll
        for (int h = 0; h < H; ++h) {
            e[h] = act ? __expf(v[h] - m[h]) : 0.f;
            s[h] = e[h];
#pragma unroll
            for (int off = 32; off >= 1; off >>= 1)
                s[h] += __shfl_xor(s[h], off, 64);
        }
        float sh;
        if (H == 1) sh = s[0];
        else sh = (head == 0) ? s[0] : (head == 1) ? s[1] : (head == 2) ? s[2] : s[3];
        float inv = 1.f / (sh + 1e-16f);

        float acc[VEC];
#pragma unroll
        for (int k = 0; k < VEC; ++k) acc[k] = 0.f;

        unsigned int eb0 = __float_as_uint(e[0]);
        unsigned int eb1 = (H == 4) ? __float_as_uint(e[1]) : 0u;
        unsigned int eb2 = (H == 4) ? __float_as_uint(e[2]) : 0u;
        unsigned int eb3 = (H == 4) ? __float_as_uint(e[3]) : 0u;

        for (int j = 0; j < deg; ++j) {
            int snj = __builtin_amdgcn_readlane(sn, j);
            float exj;
            if (H == 1) {
                exj = __uint_as_float(__builtin_amdgcn_readlane(eb0, j));
            } else {
                unsigned int w0 = __builtin_amdgcn_readlane(eb0, j);
                unsigned int w1 = __builtin_amdgcn_readlane(eb1, j);
                unsigned int w2 = __builtin_amdgcn_readlane(eb2, j);
                unsigned int w3 = __builtin_amdgcn_readlane(eb3, j);
                unsigned int ws_ = (head < 2) ? ((head == 0) ? w0 : w1)
                                              : ((head == 2) ? w2 : w3);
                exj = __uint_as_float(ws_);
            }
            if (H == 4) {
                const ushort4 u = *reinterpret_cast<const ushort4*>(Hb + (size_t)snj * 256 + lane * 4);
                acc[0] += exj * bf2f(u.x);
                acc[1] += exj * bf2f(u.y);
                acc[2] += exj * bf2f(u.z);
                acc[3] += exj * bf2f(u.w);
            } else {
                acc[0] += exj * bf2f(Hb[(size_t)snj * 64 + lane]);
            }
        }

        if (H == 4) {
            ushort4 o;
            float t0 = acc[0] * inv + bias[lane * 4 + 0]; o.x = f2bf(t0 > 0.f ? t0 : 0.f);
            float t1 = acc[1] * inv + bias[lane * 4 + 1]; o.y = f2bf(t1 > 0.f ? t1 : 0.f);
            float t2 = acc[2] * inv + bias[lane * 4 + 2]; o.z = f2bf(t2 > 0.f ? t2 : 0.f);
            float t3 = acc[3] * inv + bias[lane * 4 + 3]; o.w = f2bf(t3 > 0.f ? t3 : 0.f);
            *reinterpret_cast<ushort4*>(out + (size_t)node * 256 + lane * 4) = o;
        } else {
            float t = acc[0] * inv + bias[lane];
            out[(size_t)node * 64 + lane] = f2bf(t > 0.f ? t : 0.f);
        }
        return;
    }

    // -------- slow path (deg > 64): generic two-pass --------
    float m[H], s[H];
#pragma unroll
    for (int h = 0; h < H; ++h) { m[h] = -1e30f; s[h] = 0.f; }
    for (int j = start + lane; j < end; j += 64) {
        int sn = csr_src[j];
#pragma unroll
        for (int h = 0; h < H; ++h) {
            float t = a_s[(size_t)sn * H + h] + adn[h];
            t = (t > 0.f) ? t : NEG_SLOPE * t;
            m[h] = fmaxf(m[h], t);
        }
    }
#pragma unroll
    for (int off = 32; off >= 1; off >>= 1)
#pragma unroll
        for (int h = 0; h < H; ++h) m[h] = fmaxf(m[h], __shfl_xor(m[h], off, 64));
    for (int j = start + lane; j < end; j += 64) {
        int sn = csr_src[j];
#pragma unroll
        for (int h = 0; h < H; ++h) {
            float t = a_s[(size_t)sn * H + h] + adn[h];
            t = (t > 0.f) ? t : NEG_SLOPE * t;
            s[h] += __expf(t - m[h]);
        }
    }
#pragma unroll
    for (int off = 32; off >= 1; off >>= 1)
#pragma unroll
        for (int h = 0; h < H; ++h) s[h] += __shfl_xor(s[h], off, 64);

    float mh, sh, adh;
    if (H == 1) { mh = m[0]; sh = s[0]; adh = adn[0]; }
    else {
        mh  = (head == 0) ? m[0]   : (head == 1) ? m[1]   : (head == 2) ? m[2]   : m[3];
        sh  = (head == 0) ? s[0]   : (head == 1) ? s[1]   : (head == 2) ? s[2]   : s[3];
        adh = (head == 0) ? adn[0] : (head == 1) ? adn[1] : (head == 2) ? adn[2] : adn[3];
    }
    float inv = 1.f / (sh + 1e-16f);
    float acc[VEC];
#pragma unroll
    for (int k = 0; k < VEC; ++k) acc[k] = 0.f;
    for (int j = start; j < end; ++j) {
        int sn = csr_src[j];
        float t = a_s[(size_t)sn * H + head] + adh;
        t = (t > 0.f) ? t : NEG_SLOPE * t;
        float ex = __expf(t - mh);
        const unsigned short* hp = Hb + (size_t)sn * F + lane * VEC;
#pragma unroll
        for (int k = 0; k < VEC; ++k) acc[k] += ex * bf2f(hp[k]);
    }
#pragma unroll
    for (int k = 0; k < VEC; ++k) {
        int f = lane * VEC + k;
        float t = acc[k] * inv + bias[f];
        out[(size_t)node * F + f] = f2bf(t > 0.f ? t : 0.f);
    }
}

// ---------------- global mean pool (sums, bf16 input) ----------------
__global__ void pool_kernel(const unsigned short* __restrict__ x, const int* __restrict__ batch,
                            float* __restrict__ gsums, int Nn)
{
    int lane = threadIdx.x;        // blockDim = 64
    int n0 = blockIdx.x * 64;
    if (n0 >= Nn) return;
    int nend = min(n0 + 64, Nn);
    float acc = 0.f;
    int gcur = batch[n0];
    for (int n = n0; n < nend; ++n) {
        int g = batch[n];
        if (g != gcur) {
            atomicAdd(&gsums[gcur * 64 + lane], acc);
            acc = 0.f;
            gcur = g;
        }
        acc += bf2f(x[(size_t)n * 64 + lane]);
    }
    atomicAdd(&gsums[gcur * 64 + lane], acc);
}

// ---------------- final linear ----------------
__global__ void final_kernel(const float* __restrict__ gsums, const int* __restrict__ gcnt,
                             const float* __restrict__ linW, const float* __restrict__ linb,
                             float* __restrict__ out, int G)
{
    int t = threadIdx.x;
    if (t >= G * 10) return;
    int g = t / 10, j = t % 10;
    float cnt = (float)max(gcnt[g], 1);
    float acc = 0.f;
#pragma unroll
    for (int c = 0; c < 64; ++c) acc += gsums[g * 64 + c] * linW[j * 64 + c];
    out[g * 10 + j] = acc / cnt + linb[j];
}

extern "C" void kernel_launch(void* const* d_in, const int* in_sizes, int n_in,
                              void* d_out, int out_size, void* d_ws, size_t ws_size,
                              hipStream_t stream)
{
    const int*   x_ids    = (const int*)d_in[0];
    const float* degrees  = (const float*)d_in[1];
    const int*   edge_src = (const int*)d_in[2];
    const int*   edge_dst = (const int*)d_in[3];
    const int*   batch    = (const int*)d_in[4];
    const float* emb      = (const float*)d_in[5];
    const float* W1  = (const float*)d_in[6];
    const float* as1 = (const float*)d_in[7];
    const float* ad1 = (const float*)d_in[8];
    const float* b1  = (const float*)d_in[9];
    const float* W2  = (const float*)d_in[10];
    const float* as2 = (const float*)d_in[11];
    const float* ad2 = (const float*)d_in[12];
    const float* b2  = (const float*)d_in[13];
    const float* W3  = (const float*)d_in[14];
    const float* as3 = (const float*)d_in[15];
    const float* ad3 = (const float*)d_in[16];
    const float* b3  = (const float*)d_in[17];
    const float* linW = (const float*)d_in[18];
    const float* linb = (const float*)d_in[19];

    const int N  = in_sizes[0];
    const int E0 = in_sizes[2];
    const int E2 = E0 + N;
    const int G  = out_size / 10;
    const int nW1 = in_sizes[6], nW2 = in_sizes[10], nW3 = in_sizes[14];

    char* p = (char*)d_ws;
    size_t off = 0;
    auto take = [&](size_t bytes) {
        void* q = p + off;
        off = (off + bytes + 255) & ~(size_t)255;
        return q;
    };
    unsigned short* xA  = (unsigned short*)take((size_t)N * 256 * 2);
    unsigned short* xB  = (unsigned short*)take((size_t)N * 256 * 2);
    float* a_s     = (float*)take((size_t)N * 4 * 4);
    float* a_d     = (float*)take((size_t)N * 4 * 4);
    int*   cnt     = (int*)take((size_t)N * 4);
    int*   row_off = (int*)take((size_t)(N + 1) * 4);
    int*   cursor  = (int*)take((size_t)N * 4);
    int*   csr_src = (int*)take((size_t)E2 * 4);
    float* gsums   = (float*)take((size_t)G * 64 * 4);
    int*   gcnt    = (int*)take((size_t)G * 4);
    int*   part    = (int*)take((size_t)64 * 4);
    unsigned short* w1b = (unsigned short*)take((size_t)nW1 * 2);
    unsigned short* w2b = (unsigned short*)take((size_t)nW2 * 2);
    unsigned short* w3b = (unsigned short*)take((size_t)nW3 * 2);

    hipMemsetAsync(cnt, 0, (size_t)N * 4, stream);
    hipMemsetAsync(gsums, 0, (size_t)G * 64 * 4, stream);

    const int nodeBlocks4 = (N + 3) / 4;
    const int edgeBlocks  = (E2 + 255) / 256;
    const int scanBlocks  = (N + 2047) / 2048;

    f2bf_kernel<<<(nW1 + 255) / 256, 256, 0, stream>>>(W1, w1b, nW1);
    f2bf_kernel<<<(nW2 + 255) / 256, 256, 0, stream>>>(W2, w2b, nW2);
    f2bf_kernel<<<(nW3 + 255) / 256, 256, 0, stream>>>(W3, w3b, nW3);

    build_x_kernel<<<nodeBlocks4, 256, 0, stream>>>(x_ids, degrees, emb, xA, N);
    hist_dst_kernel<<<edgeBlocks, 256, 0, stream>>>(edge_dst, cnt, E0, E2);
    gcnt_kernel<<<1, 64, 0, stream>>>(batch, gcnt, N, G);
    scan_part_kernel<<<scanBlocks, 256, 0, stream>>>(cnt, part, N);
    scan_top_kernel<<<1, 64, 0, stream>>>(part, scanBlocks);
    scan_down_kernel<<<scanBlocks, 256, 0, stream>>>(cnt, part, row_off, cursor, N, E2);
    scatter_kernel<<<edgeBlocks, 256, 0, stream>>>(edge_src, edge_dst, cursor, csr_src, E0, E2);

    const int mtiles = (N + 15) / 16;
    auto gemmBlocks = [&](int ftiles) { return (mtiles * ftiles + 3) / 4; };

    // ---- layer 1: 64 -> 4x64 concat ----
    gemm_mfma<<<gemmBlocks(4), 256, 0, stream>>>(xA, w1b, xB, as1, ad1, a_s, a_d, N, 64, 256);
    aggregate_kernel<4><<<nodeBlocks4, 256, 0, stream>>>(xB, a_s, a_d, row_off, csr_src, b1, xA, N);
    // ---- layer 2: 256 -> 4x64 concat ----
    gemm_mfma<<<gemmBlocks(4), 256, 0, stream>>>(xA, w2b, xB, as2, ad2, a_s, a_d, N, 256, 256);
    aggregate_kernel<4><<<nodeBlocks4, 256, 0, stream>>>(xB, a_s, a_d, row_off, csr_src, b2, xA, N);
    // ---- layer 3: 256 -> 1x64 (mean == identity) ----
    gemm_mfma<<<gemmBlocks(1), 256, 0, stream>>>(xA, w3b, xB, as3, ad3, a_s, a_d, N, 256, 64);
    aggregate_kernel<1><<<nodeBlocks4, 256, 0, stream>>>(xB, a_s, a_d, row_off, csr_src, b3, xA, N);

    pool_kernel<<<(N + 63) / 64, 64, 0, stream>>>(xA, batch, gsums, N);
    final_kernel<<<1, ((G * 10 + 63) / 64) * 64, 0, stream>>>(gsums, gcnt, linW, linb, (float*)d_out, G);
}

// Round 5
// 391.832 us; speedup vs baseline: 3.0646x; 1.2086x over previous
//
#include <hip/hip_runtime.h>
#include <hip/hip_bf16.h>
#include <cstdint>

#define NEG_SLOPE 0.2f

typedef __bf16 bf16x8 __attribute__((ext_vector_type(8)));
typedef float  f32x4  __attribute__((ext_vector_type(4)));

__device__ __forceinline__ unsigned short f2bf(float f) {
    unsigned int u = __float_as_uint(f);
    u += 0x7fffu + ((u >> 16) & 1u);          // round-to-nearest-even
    return (unsigned short)(u >> 16);
}
__device__ __forceinline__ float bf2f(unsigned short u) {
    return __uint_as_float((unsigned int)u << 16);
}

// ---------------- prep mega-kernel: f2bf(W1,W2,W3) + build_x + hist + gcnt ----------------
__global__ void prep_kernel(const float* __restrict__ W1, int n1,
                            const float* __restrict__ W2, int n2,
                            const float* __restrict__ W3, int n3,
                            unsigned short* __restrict__ w1b, unsigned short* __restrict__ w2b,
                            unsigned short* __restrict__ w3b,
                            const int* __restrict__ ids, const float* __restrict__ degs,
                            const float* __restrict__ emb, unsigned short* __restrict__ x,
                            const int* __restrict__ edst, int* __restrict__ cnt,
                            const int* __restrict__ batch, int* __restrict__ gcnt,
                            int Nn, int E0, int E2, int G,
                            int bW, int bX, int bH)
{
    int b = blockIdx.x;
    if (b < bW) {
        int i = b * 256 + threadIdx.x;
        if (i < n1) w1b[i] = f2bf(W1[i]);
        int j = i - n1;
        if (j >= 0 && j < n2) w2b[j] = f2bf(W2[j]);
        int k = j - n2;
        if (k >= 0 && k < n3) w3b[k] = f2bf(W3[k]);
    } else if (b < bX) {
        int node = (b - bW) * 4 + (threadIdx.x >> 6);
        int lane = threadIdx.x & 63;
        if (node < Nn) {
            int id = ids[node];
            float v;
            if (lane < 62) v = emb[(size_t)id * 62 + lane];
            else           v = degs[node * 2 + (lane - 62)];
            x[(size_t)node * 64 + lane] = f2bf(v);
        }
    } else if (b < bH) {
        int e = (b - bX) * 256 + threadIdx.x;
        if (e < E2) {
            int d = (e < E0) ? edst[e] : (e - E0);
            atomicAdd(&cnt[d], 1);
        }
    } else {
        int g = threadIdx.x;
        if (g < G) {
            int lo0 = 0, hi = Nn;
            while (lo0 < hi) { int mid = (lo0 + hi) >> 1; if (batch[mid] < g) lo0 = mid + 1; else hi = mid; }
            int lo1 = lo0; hi = Nn;
            while (lo1 < hi) { int mid = (lo1 + hi) >> 1; if (batch[mid] < g + 1) lo1 = mid + 1; else hi = mid; }
            gcnt[g] = lo1 - lo0;
        }
    }
}

// ---------------- hierarchical exclusive scan (3 kernels) ----------------
__global__ void scan_part_kernel(const int* __restrict__ cnt, int* __restrict__ part, int Nn)
{
    int t = threadIdx.x;                   // 256 threads
    int base = blockIdx.x * 2048 + t * 8;
    int s = 0;
    if (base + 8 <= Nn) {
        int4 a = *reinterpret_cast<const int4*>(cnt + base);
        int4 b = *reinterpret_cast<const int4*>(cnt + base + 4);
        s = a.x + a.y + a.z + a.w + b.x + b.y + b.z + b.w;
    } else {
        for (int k = 0; k < 8; ++k)
            if (base + k < Nn) s += cnt[base + k];
    }
#pragma unroll
    for (int off = 32; off >= 1; off >>= 1) s += __shfl_xor(s, off, 64);
    __shared__ int ws[4];
    int wid = t >> 6;
    if ((t & 63) == 0) ws[wid] = s;
    __syncthreads();
    if (t == 0) part[blockIdx.x] = ws[0] + ws[1] + ws[2] + ws[3];
}

__global__ void scan_top_kernel(int* __restrict__ part, int nparts)
{
    int t = threadIdx.x;                   // 64 threads
    int v = (t < nparts) ? part[t] : 0;
    int orig = v;
#pragma unroll
    for (int off = 1; off <= 32; off <<= 1) {
        int u = __shfl_up(v, off, 64);
        if (t >= off) v += u;
    }
    if (t < nparts) part[t] = v - orig;    // exclusive
}

__global__ void scan_down_kernel(const int* __restrict__ cnt, const int* __restrict__ part,
                                 int* __restrict__ row_off, int* __restrict__ cursor,
                                 int Nn, int total)
{
    int t = threadIdx.x;                   // 256 threads
    int base = blockIdx.x * 2048 + t * 8;
    int v[8];
    if (base + 8 <= Nn) {
        int4 a = *reinterpret_cast<const int4*>(cnt + base);
        int4 b = *reinterpret_cast<const int4*>(cnt + base + 4);
        v[0]=a.x; v[1]=a.y; v[2]=a.z; v[3]=a.w; v[4]=b.x; v[5]=b.y; v[6]=b.z; v[7]=b.w;
    } else {
#pragma unroll
        for (int k = 0; k < 8; ++k) v[k] = (base + k < Nn) ? cnt[base + k] : 0;
    }
    int tsum = 0;
#pragma unroll
    for (int k = 0; k < 8; ++k) tsum += v[k];
    int incl = tsum;
#pragma unroll
    for (int off = 1; off <= 32; off <<= 1) {
        int u = __shfl_up(incl, off, 64);
        if ((t & 63) >= off) incl += u;
    }
    int texcl = incl - tsum;
    __shared__ int ws[4];
    int wid = t >> 6;
    if ((t & 63) == 63) ws[wid] = incl;
    __syncthreads();
    int wbase = 0;
#pragma unroll
    for (int w = 0; w < 4; ++w) wbase += (w < wid) ? ws[w] : 0;
    int run = part[blockIdx.x] + wbase + texcl;

    if (base + 8 <= Nn) {
        int o[8];
#pragma unroll
        for (int k = 0; k < 8; ++k) { o[k] = run; run += v[k]; }
        *reinterpret_cast<int4*>(row_off + base)     = make_int4(o[0], o[1], o[2], o[3]);
        *reinterpret_cast<int4*>(row_off + base + 4) = make_int4(o[4], o[5], o[6], o[7]);
        *reinterpret_cast<int4*>(cursor + base)      = make_int4(o[0], o[1], o[2], o[3]);
        *reinterpret_cast<int4*>(cursor + base + 4)  = make_int4(o[4], o[5], o[6], o[7]);
    } else {
#pragma unroll
        for (int k = 0; k < 8; ++k) {
            if (base + k < Nn) {
                row_off[base + k] = run;
                cursor[base + k]  = run;
                run += v[k];
            }
        }
    }
    if (blockIdx.x == 0 && t == 0) row_off[Nn] = total;
}

__global__ void scatter_kernel(const int* __restrict__ esrc, const int* __restrict__ edst,
                               int* __restrict__ cursor, int* __restrict__ csr_src,
                               int E0, int E2)
{
    int e = blockIdx.x * blockDim.x + threadIdx.x;
    if (e >= E2) return;
    int s, d;
    if (e < E0) { s = esrc[e]; d = edst[e]; }
    else        { s = d = e - E0; }
    int pos = atomicAdd(&cursor[d], 1);
    csr_src[pos] = s;
}

// ---------------- bf16 MFMA GEMM: 64x64 output tile per wave ----------------
__global__ void gemm_mfma(const unsigned short* __restrict__ X, const unsigned short* __restrict__ Wb,
                          unsigned short* __restrict__ Hout,
                          const float* __restrict__ aSrc, const float* __restrict__ aDst,
                          float* __restrict__ a_s, float* __restrict__ a_d,
                          int Nn, int K, int F)
{
    int wid  = (blockIdx.x * blockDim.x + threadIdx.x) >> 6;
    int lane = threadIdx.x & 63;
    int mtiles = (Nn + 63) >> 6;
    int ftiles = F >> 6;
    if (wid >= mtiles * ftiles) return;
    int ft = wid / mtiles;
    int mt = wid - ft * mtiles;
    int m0 = mt << 6, f0 = ft << 6;
    int r = lane & 15, g = lane >> 4, g4 = g << 2;

    const unsigned short* xrow[4];
#pragma unroll
    for (int ja = 0; ja < 4; ++ja) {
        int row = m0 + ja * 16 + r;
        if (row >= Nn) row = Nn - 1;
        xrow[ja] = X + (size_t)row * K + g * 8;
    }
    const unsigned short* wrow = Wb + (size_t)(f0 + r) * K + g * 8;
    const size_t wstep = (size_t)16 * K;

    f32x4 acc[4][4];
#pragma unroll
    for (int a = 0; a < 4; ++a)
#pragma unroll
        for (int b = 0; b < 4; ++b) acc[a][b] = f32x4{0.f, 0.f, 0.f, 0.f};

    for (int k0 = 0; k0 < K; k0 += 32) {
        bf16x8 av[4], bv[4];
#pragma unroll
        for (int ja = 0; ja < 4; ++ja) av[ja] = *reinterpret_cast<const bf16x8*>(xrow[ja] + k0);
#pragma unroll
        for (int jb = 0; jb < 4; ++jb) bv[jb] = *reinterpret_cast<const bf16x8*>(wrow + jb * wstep + k0);
#pragma unroll
        for (int ja = 0; ja < 4; ++ja)
#pragma unroll
            for (int jb = 0; jb < 4; ++jb)
                acc[ja][jb] = __builtin_amdgcn_mfma_f32_16x16x32_bf16(av[ja], bv[jb], acc[ja][jb], 0, 0, 0);
    }

    // store H (bf16). C/D layout: col = r, row = g4 + q (within each 16x16).
#pragma unroll
    for (int ja = 0; ja < 4; ++ja)
#pragma unroll
        for (int q = 0; q < 4; ++q) {
            int row = m0 + ja * 16 + g4 + q;
            if (row < Nn) {
#pragma unroll
                for (int jb = 0; jb < 4; ++jb)
                    Hout[(size_t)row * F + f0 + jb * 16 + r] = f2bf(acc[ja][jb][q]);
            }
        }

    // fused attention-coefficient epilogue (fp32)
    float ps[4][4], pd[4][4];
#pragma unroll
    for (int ja = 0; ja < 4; ++ja)
#pragma unroll
        for (int q = 0; q < 4; ++q) { ps[ja][q] = 0.f; pd[ja][q] = 0.f; }
#pragma unroll
    for (int jb = 0; jb < 4; ++jb) {
        float ws_ = aSrc[f0 + jb * 16 + r];
        float wd_ = aDst[f0 + jb * 16 + r];
#pragma unroll
        for (int ja = 0; ja < 4; ++ja)
#pragma unroll
            for (int q = 0; q < 4; ++q) {
                ps[ja][q] += acc[ja][jb][q] * ws_;
                pd[ja][q] += acc[ja][jb][q] * wd_;
            }
    }
#pragma unroll
    for (int off = 1; off < 16; off <<= 1)
#pragma unroll
        for (int ja = 0; ja < 4; ++ja)
#pragma unroll
            for (int q = 0; q < 4; ++q) {
                ps[ja][q] += __shfl_xor(ps[ja][q], off, 64);
                pd[ja][q] += __shfl_xor(pd[ja][q], off, 64);
            }
    if (r == 0) {
        int Hh = F >> 6;
#pragma unroll
        for (int ja = 0; ja < 4; ++ja)
#pragma unroll
            for (int q = 0; q < 4; ++q) {
                int n = m0 + ja * 16 + g4 + q;
                if (n < Nn) {
                    a_s[(size_t)n * Hh + ft] = ps[ja][q];
                    a_d[(size_t)n * Hh + ft] = pd[ja][q];
                }
            }
    }
}

// ---------------- softmax + weighted aggregation (bf16 H, fp32 scores) ----------------
template<int H>
__global__ void aggregate_kernel(const unsigned short* __restrict__ Hb,
                                 const float* __restrict__ a_s, const float* __restrict__ a_d,
                                 const int* __restrict__ row_off, const int* __restrict__ csr_src,
                                 const float* __restrict__ bias,
                                 unsigned short* __restrict__ out, int Nn)
{
    constexpr int F = H * 64;
    constexpr int VEC = F / 64;
    __shared__ int   s_sn[4][64];
    __shared__ float s_e[4][64][H];
    int w = threadIdx.x >> 6;
    int node = blockIdx.x * 4 + w;
    int lane = threadIdx.x & 63;
    if (node >= Nn) return;
    int start = row_off[node], end = row_off[node + 1];
    int deg = end - start;

    float adn[H];
#pragma unroll
    for (int h = 0; h < H; ++h) adn[h] = a_d[(size_t)node * H + h];

    if (deg <= 64) {
        // -------- fast path --------
        bool act = lane < deg;
        int sn = act ? csr_src[start + lane] : 0;
        float v[H];
        if (H == 4) {
            const f32x4 av = *reinterpret_cast<const f32x4*>(a_s + (size_t)sn * 4);
#pragma unroll
            for (int h = 0; h < 4; ++h) {
                float t = av[h] + adn[h];
                t = (t > 0.f) ? t : NEG_SLOPE * t;
                v[h] = act ? t : -1e30f;
            }
        } else {
            float t = a_s[sn] + adn[0];
            t = (t > 0.f) ? t : NEG_SLOPE * t;
            v[0] = act ? t : -1e30f;
        }
        float m[H], e[H], s[H];
#pragma unroll
        for (int h = 0; h < H; ++h) {
            m[h] = v[h];
#pragma unroll
            for (int off = 32; off >= 1; off >>= 1)
                m[h] = fmaxf(m[h], __shfl_xor(m[h], off, 64));
        }
#pragma unroll
        for (int h = 0; h < H; ++h) {
            e[h] = act ? __expf(v[h] - m[h]) : 0.f;
            s[h] = e[h];
#pragma unroll
            for (int off = 32; off >= 1; off >>= 1)
                s[h] += __shfl_xor(s[h], off, 64);
        }

        // stage edge data in LDS (own-wave slice)
        s_sn[w][lane] = sn;
#pragma unroll
        for (int h = 0; h < H; ++h) s_e[w][lane][h] = e[h];
        asm volatile("s_waitcnt lgkmcnt(0)" ::: "memory");

        if (H == 4) {
            // 2 edges / iter: lanes 0-31 -> edge j, lanes 32-63 -> edge j+1; 8 ch/lane
            int half = lane >> 5, laneh = lane & 31, hd = laneh >> 3;
            float acc[8];
#pragma unroll
            for (int k = 0; k < 8; ++k) acc[k] = 0.f;
            for (int j = 0; j < deg; j += 2) {
                int idx = j + half;
                int snj = s_sn[w][idx];
                float ex = s_e[w][idx][hd];
                const uint4 u = *reinterpret_cast<const uint4*>(Hb + (size_t)snj * 256 + laneh * 8);
                acc[0] += ex * __uint_as_float(u.x << 16);
                acc[1] += ex * __uint_as_float(u.x & 0xffff0000u);
                acc[2] += ex * __uint_as_float(u.y << 16);
                acc[3] += ex * __uint_as_float(u.y & 0xffff0000u);
                acc[4] += ex * __uint_as_float(u.z << 16);
                acc[5] += ex * __uint_as_float(u.z & 0xffff0000u);
                acc[6] += ex * __uint_as_float(u.w << 16);
                acc[7] += ex * __uint_as_float(u.w & 0xffff0000u);
            }
#pragma unroll
            for (int k = 0; k < 8; ++k) acc[k] += __shfl_xor(acc[k], 32, 64);
            if (lane < 32) {
                float sh = (hd == 0) ? s[0] : (hd == 1) ? s[1] : (hd == 2) ? s[2] : s[3];
                float inv = 1.f / (sh + 1e-16f);
                unsigned int pk[4];
#pragma unroll
                for (int k = 0; k < 4; ++k) {
                    float t0 = acc[2*k]   * inv + bias[laneh * 8 + 2*k];
                    float t1 = acc[2*k+1] * inv + bias[laneh * 8 + 2*k + 1];
                    unsigned int lo = f2bf(t0 > 0.f ? t0 : 0.f);
                    unsigned int hi = f2bf(t1 > 0.f ? t1 : 0.f);
                    pk[k] = lo | (hi << 16);
                }
                *reinterpret_cast<uint4*>(out + (size_t)node * 256 + laneh * 8) =
                    make_uint4(pk[0], pk[1], pk[2], pk[3]);
            }
        } else {
            // 4 edges / iter: 16 lanes per edge; 4 ch/lane
            int qtr = lane >> 4, laneq = lane & 15;
            float acc[4];
#pragma unroll
            for (int k = 0; k < 4; ++k) acc[k] = 0.f;
            for (int j = 0; j < deg; j += 4) {
                int idx = j + qtr;
                int snj = s_sn[w][idx];
                float ex = s_e[w][idx][0];
                const uint2 u = *reinterpret_cast<const uint2*>(Hb + (size_t)snj * 64 + laneq * 4);
                acc[0] += ex * __uint_as_float(u.x << 16);
                acc[1] += ex * __uint_as_float(u.x & 0xffff0000u);
                acc[2] += ex * __uint_as_float(u.y << 16);
                acc[3] += ex * __uint_as_float(u.y & 0xffff0000u);
            }
#pragma unroll
            for (int k = 0; k < 4; ++k) {
                acc[k] += __shfl_xor(acc[k], 32, 64);
                acc[k] += __shfl_xor(acc[k], 16, 64);
            }
            if (lane < 16) {
                float inv = 1.f / (s[0] + 1e-16f);
                unsigned int pk[2];
#pragma unroll
                for (int k = 0; k < 2; ++k) {
                    float t0 = acc[2*k]   * inv + bias[laneq * 4 + 2*k];
                    float t1 = acc[2*k+1] * inv + bias[laneq * 4 + 2*k + 1];
                    unsigned int lo = f2bf(t0 > 0.f ? t0 : 0.f);
                    unsigned int hi = f2bf(t1 > 0.f ? t1 : 0.f);
                    pk[k] = lo | (hi << 16);
                }
                *reinterpret_cast<uint2*>(out + (size_t)node * 64 + laneq * 4) =
                    make_uint2(pk[0], pk[1]);
            }
        }
        return;
    }

    // -------- slow path (deg > 64): generic two-pass --------
    int head = (H == 1) ? 0 : (lane >> 4);
    float m[H], s[H];
#pragma unroll
    for (int h = 0; h < H; ++h) { m[h] = -1e30f; s[h] = 0.f; }
    for (int j = start + lane; j < end; j += 64) {
        int sn = csr_src[j];
#pragma unroll
        for (int h = 0; h < H; ++h) {
            float t = a_s[(size_t)sn * H + h] + adn[h];
            t = (t > 0.f) ? t : NEG_SLOPE * t;
            m[h] = fmaxf(m[h], t);
        }
    }
#pragma unroll
    for (int off = 32; off >= 1; off >>= 1)
#pragma unroll
        for (int h = 0; h < H; ++h) m[h] = fmaxf(m[h], __shfl_xor(m[h], off, 64));
    for (int j = start + lane; j < end; j += 64) {
        int sn = csr_src[j];
#pragma unroll
        for (int h = 0; h < H; ++h) {
            float t = a_s[(size_t)sn * H + h] + adn[h];
            t = (t > 0.f) ? t : NEG_SLOPE * t;
            s[h] += __expf(t - m[h]);
        }
    }
#pragma unroll
    for (int off = 32; off >= 1; off >>= 1)
#pragma unroll
        for (int h = 0; h < H; ++h) s[h] += __shfl_xor(s[h], off, 64);

    float mh, sh, adh;
    if (H == 1) { mh = m[0]; sh = s[0]; adh = adn[0]; }
    else {
        mh  = (head == 0) ? m[0]   : (head == 1) ? m[1]   : (head == 2) ? m[2]   : m[3];
        sh  = (head == 0) ? s[0]   : (head == 1) ? s[1]   : (head == 2) ? s[2]   : s[3];
        adh = (head == 0) ? adn[0] : (head == 1) ? adn[1] : (head == 2) ? adn[2] : adn[3];
    }
    float inv = 1.f / (sh + 1e-16f);
    float acc[VEC];
#pragma unroll
    for (int k = 0; k < VEC; ++k) acc[k] = 0.f;
    for (int j = start; j < end; ++j) {
        int sn = csr_src[j];
        float t = a_s[(size_t)sn * H + head] + adh;
        t = (t > 0.f) ? t : NEG_SLOPE * t;
        float ex = __expf(t - mh);
        const unsigned short* hp = Hb + (size_t)sn * F + lane * VEC;
#pragma unroll
        for (int k = 0; k < VEC; ++k) acc[k] += ex * bf2f(hp[k]);
    }
#pragma unroll
    for (int k = 0; k < VEC; ++k) {
        int f = lane * VEC + k;
        float t = acc[k] * inv + bias[f];
        out[(size_t)node * F + f] = f2bf(t > 0.f ? t : 0.f);
    }
}

// ---------------- global mean pool (sums, bf16 input) ----------------
__global__ void pool_kernel(const unsigned short* __restrict__ x, const int* __restrict__ batch,
                            float* __restrict__ gsums, int Nn)
{
    int lane = threadIdx.x;        // blockDim = 64
    int n0 = blockIdx.x * 64;
    if (n0 >= Nn) return;
    int nend = min(n0 + 64, Nn);
    float acc = 0.f;
    int gcur = batch[n0];
    for (int n = n0; n < nend; ++n) {
        int g = batch[n];
        if (g != gcur) {
            atomicAdd(&gsums[gcur * 64 + lane], acc);
            acc = 0.f;
            gcur = g;
        }
        acc += bf2f(x[(size_t)n * 64 + lane]);
    }
    atomicAdd(&gsums[gcur * 64 + lane], acc);
}

// ---------------- final linear ----------------
__global__ void final_kernel(const float* __restrict__ gsums, const int* __restrict__ gcnt,
                             const float* __restrict__ linW, const float* __restrict__ linb,
                             float* __restrict__ out, int G)
{
    int t = threadIdx.x;
    if (t >= G * 10) return;
    int g = t / 10, j = t % 10;
    float cnt = (float)max(gcnt[g], 1);
    float acc = 0.f;
#pragma unroll
    for (int c = 0; c < 64; ++c) acc += gsums[g * 64 + c] * linW[j * 64 + c];
    out[g * 10 + j] = acc / cnt + linb[j];
}

extern "C" void kernel_launch(void* const* d_in, const int* in_sizes, int n_in,
                              void* d_out, int out_size, void* d_ws, size_t ws_size,
                              hipStream_t stream)
{
    const int*   x_ids    = (const int*)d_in[0];
    const float* degrees  = (const float*)d_in[1];
    const int*   edge_src = (const int*)d_in[2];
    const int*   edge_dst = (const int*)d_in[3];
    const int*   batch    = (const int*)d_in[4];
    const float* emb      = (const float*)d_in[5];
    const float* W1  = (const float*)d_in[6];
    const float* as1 = (const float*)d_in[7];
    const float* ad1 = (const float*)d_in[8];
    const float* b1  = (const float*)d_in[9];
    const float* W2  = (const float*)d_in[10];
    const float* as2 = (const float*)d_in[11];
    const float* ad2 = (const float*)d_in[12];
    const float* b2  = (const float*)d_in[13];
    const float* W3  = (const float*)d_in[14];
    const float* as3 = (const float*)d_in[15];
    const float* ad3 = (const float*)d_in[16];
    const float* b3  = (const float*)d_in[17];
    const float* linW = (const float*)d_in[18];
    const float* linb = (const float*)d_in[19];

    const int N  = in_sizes[0];
    const int E0 = in_sizes[2];
    const int E2 = E0 + N;
    const int G  = out_size / 10;
    const int nW1 = in_sizes[6], nW2 = in_sizes[10], nW3 = in_sizes[14];

    char* p = (char*)d_ws;
    size_t off = 0;
    auto take = [&](size_t bytes) {
        void* q = p + off;
        off = (off + bytes + 255) & ~(size_t)255;
        return q;
    };
    unsigned short* xA  = (unsigned short*)take((size_t)N * 256 * 2);
    unsigned short* xB  = (unsigned short*)take((size_t)N * 256 * 2);
    float* a_s     = (float*)take((size_t)N * 4 * 4);
    float* a_d     = (float*)take((size_t)N * 4 * 4);
    int*   cnt     = (int*)take((size_t)N * 4);
    int*   row_off = (int*)take((size_t)(N + 1) * 4);
    int*   cursor  = (int*)take((size_t)N * 4);
    int*   csr_src = (int*)take((size_t)E2 * 4);
    float* gsums   = (float*)take((size_t)G * 64 * 4);
    int*   gcnt    = (int*)take((size_t)G * 4);
    int*   part    = (int*)take((size_t)64 * 4);
    unsigned short* w1b = (unsigned short*)take((size_t)nW1 * 2);
    unsigned short* w2b = (unsigned short*)take((size_t)nW2 * 2);
    unsigned short* w3b = (unsigned short*)take((size_t)nW3 * 2);

    hipMemsetAsync(cnt, 0, (size_t)N * 4, stream);
    hipMemsetAsync(gsums, 0, (size_t)G * 64 * 4, stream);

    const int nodeBlocks4 = (N + 3) / 4;
    const int edgeBlocks  = (E2 + 255) / 256;
    const int scanBlocks  = (N + 2047) / 2048;

    // prep mega-kernel block partition
    const int nWtot = nW1 + nW2 + nW3;
    const int bW = (nWtot + 255) / 256;
    const int bX = bW + nodeBlocks4;
    const int bH = bX + edgeBlocks;
    prep_kernel<<<bH + 1, 256, 0, stream>>>(W1, nW1, W2, nW2, W3, nW3, w1b, w2b, w3b,
                                            x_ids, degrees, emb, xA,
                                            edge_dst, cnt, batch, gcnt,
                                            N, E0, E2, G, bW, bX, bH);

    scan_part_kernel<<<scanBlocks, 256, 0, stream>>>(cnt, part, N);
    scan_top_kernel<<<1, 64, 0, stream>>>(part, scanBlocks);
    scan_down_kernel<<<scanBlocks, 256, 0, stream>>>(cnt, part, row_off, cursor, N, E2);
    scatter_kernel<<<edgeBlocks, 256, 0, stream>>>(edge_src, edge_dst, cursor, csr_src, E0, E2);

    const int mtiles = (N + 63) / 64;
    auto gemmBlocks = [&](int ftiles) { return (mtiles * ftiles + 3) / 4; };

    // ---- layer 1: 64 -> 4x64 concat ----
    gemm_mfma<<<gemmBlocks(4), 256, 0, stream>>>(xA, w1b, xB, as1, ad1, a_s, a_d, N, 64, 256);
    aggregate_kernel<4><<<nodeBlocks4, 256, 0, stream>>>(xB, a_s, a_d, row_off, csr_src, b1, xA, N);
    // ---- layer 2: 256 -> 4x64 concat ----
    gemm_mfma<<<gemmBlocks(4), 256, 0, stream>>>(xA, w2b, xB, as2, ad2, a_s, a_d, N, 256, 256);
    aggregate_kernel<4><<<nodeBlocks4, 256, 0, stream>>>(xB, a_s, a_d, row_off, csr_src, b2, xA, N);
    // ---- layer 3: 256 -> 1x64 (mean == identity) ----
    gemm_mfma<<<gemmBlocks(1), 256, 0, stream>>>(xA, w3b, xB, as3, ad3, a_s, a_d, N, 256, 64);
    aggregate_kernel<1><<<nodeBlocks4, 256, 0, stream>>>(xB, a_s, a_d, row_off, csr_src, b3, xA, N);

    pool_kernel<<<(N + 63) / 64, 64, 0, stream>>>(xA, batch, gsums, N);
    final_kernel<<<1, ((G * 10 + 63) / 64) * 64, 0, stream>>>(gsums, gcnt, linW, linb, (float*)d_out, G);
}

// Round 6
// 372.156 us; speedup vs baseline: 3.2267x; 1.0529x over previous
//
#include <hip/hip_runtime.h>
#include <hip/hip_bf16.h>
#include <cstdint>

#define NEG_SLOPE 0.2f

typedef __bf16 bf16x8 __attribute__((ext_vector_type(8)));
typedef float  f32x4  __attribute__((ext_vector_type(4)));

__device__ __forceinline__ unsigned short f2bf(float f) {
    unsigned int u = __float_as_uint(f);
    u += 0x7fffu + ((u >> 16) & 1u);          // round-to-nearest-even
    return (unsigned short)(u >> 16);
}
__device__ __forceinline__ float bf2f(unsigned short u) {
    return __uint_as_float((unsigned int)u << 16);
}
__device__ __forceinline__ void fma2(float2& a, float ex, unsigned int u) {
    a.x = fmaf(ex, __uint_as_float(u << 16),         a.x);
    a.y = fmaf(ex, __uint_as_float(u & 0xffff0000u), a.y);
}

// ---------------- prep mega-kernel: f2bf(W) + build_x + bucket-CSR + gcnt ----------------
__global__ void prep_kernel(const float* __restrict__ W1, int n1,
                            const float* __restrict__ W2, int n2,
                            const float* __restrict__ W3, int n3,
                            unsigned short* __restrict__ w1b, unsigned short* __restrict__ w2b,
                            unsigned short* __restrict__ w3b,
                            const int* __restrict__ ids, const float* __restrict__ degs,
                            const float* __restrict__ emb, unsigned short* __restrict__ x,
                            const int* __restrict__ esrc, const int* __restrict__ edst,
                            int* __restrict__ cnt, int* __restrict__ bucket,
                            int* __restrict__ ovd, int* __restrict__ ovs, int* __restrict__ n_over,
                            const int* __restrict__ batch, int* __restrict__ gcnt,
                            int Nn, int E0, int E2, int G,
                            int bW, int bX, int bH)
{
    int b = blockIdx.x;
    if (b < bW) {
        int i = b * 256 + threadIdx.x;
        if (i < n1) w1b[i] = f2bf(W1[i]);
        int j = i - n1;
        if (j >= 0 && j < n2) w2b[j] = f2bf(W2[j]);
        int k = j - n2;
        if (k >= 0 && k < n3) w3b[k] = f2bf(W3[k]);
    } else if (b < bX) {
        int node = (b - bW) * 4 + (threadIdx.x >> 6);
        int lane = threadIdx.x & 63;
        if (node < Nn) {
            int id = ids[node];
            float v;
            if (lane < 62) v = emb[(size_t)id * 62 + lane];
            else           v = degs[node * 2 + (lane - 62)];
            x[(size_t)node * 64 + lane] = f2bf(v);
        }
    } else if (b < bH) {
        int e = (b - bX) * 256 + threadIdx.x;
        if (e < E2) {
            int s, d;
            if (e < E0) { s = esrc[e]; d = edst[e]; }
            else        { s = d = e - E0; }
            int pos = atomicAdd(&cnt[d], 1);
            if (pos < 64) bucket[(size_t)d * 64 + pos] = s;
            else {
                int o = atomicAdd(n_over, 1);
                ovd[o] = d; ovs[o] = s;
            }
        }
    } else {
        int g = threadIdx.x;
        if (g < G) {
            int lo0 = 0, hi = Nn;
            while (lo0 < hi) { int mid = (lo0 + hi) >> 1; if (batch[mid] < g) lo0 = mid + 1; else hi = mid; }
            int lo1 = lo0; hi = Nn;
            while (lo1 < hi) { int mid = (lo1 + hi) >> 1; if (batch[mid] < g + 1) lo1 = mid + 1; else hi = mid; }
            gcnt[g] = lo1 - lo0;
        }
    }
}

// ---------------- bf16 MFMA GEMM: 64x64 output tile per wave ----------------
__global__ void gemm_mfma(const unsigned short* __restrict__ X, const unsigned short* __restrict__ Wb,
                          unsigned short* __restrict__ Hout,
                          const float* __restrict__ aSrc, const float* __restrict__ aDst,
                          float* __restrict__ a_s, float* __restrict__ a_d,
                          int Nn, int K, int F)
{
    int wid  = (blockIdx.x * blockDim.x + threadIdx.x) >> 6;
    int lane = threadIdx.x & 63;
    int mtiles = (Nn + 63) >> 6;
    int ftiles = F >> 6;
    if (wid >= mtiles * ftiles) return;
    int ft = wid / mtiles;
    int mt = wid - ft * mtiles;
    int m0 = mt << 6, f0 = ft << 6;
    int r = lane & 15, g = lane >> 4, g4 = g << 2;

    const unsigned short* xrow[4];
#pragma unroll
    for (int ja = 0; ja < 4; ++ja) {
        int row = m0 + ja * 16 + r;
        if (row >= Nn) row = Nn - 1;
        xrow[ja] = X + (size_t)row * K + g * 8;
    }
    const unsigned short* wrow = Wb + (size_t)(f0 + r) * K + g * 8;
    const size_t wstep = (size_t)16 * K;

    f32x4 acc[4][4];
#pragma unroll
    for (int a = 0; a < 4; ++a)
#pragma unroll
        for (int b = 0; b < 4; ++b) acc[a][b] = f32x4{0.f, 0.f, 0.f, 0.f};

    for (int k0 = 0; k0 < K; k0 += 32) {
        bf16x8 av[4], bv[4];
#pragma unroll
        for (int ja = 0; ja < 4; ++ja) av[ja] = *reinterpret_cast<const bf16x8*>(xrow[ja] + k0);
#pragma unroll
        for (int jb = 0; jb < 4; ++jb) bv[jb] = *reinterpret_cast<const bf16x8*>(wrow + jb * wstep + k0);
#pragma unroll
        for (int ja = 0; ja < 4; ++ja)
#pragma unroll
            for (int jb = 0; jb < 4; ++jb)
                acc[ja][jb] = __builtin_amdgcn_mfma_f32_16x16x32_bf16(av[ja], bv[jb], acc[ja][jb], 0, 0, 0);
    }

#pragma unroll
    for (int ja = 0; ja < 4; ++ja)
#pragma unroll
        for (int q = 0; q < 4; ++q) {
            int row = m0 + ja * 16 + g4 + q;
            if (row < Nn) {
#pragma unroll
                for (int jb = 0; jb < 4; ++jb)
                    Hout[(size_t)row * F + f0 + jb * 16 + r] = f2bf(acc[ja][jb][q]);
            }
        }

    // fused attention-coefficient epilogue (fp32)
    float ps[4][4], pd[4][4];
#pragma unroll
    for (int ja = 0; ja < 4; ++ja)
#pragma unroll
        for (int q = 0; q < 4; ++q) { ps[ja][q] = 0.f; pd[ja][q] = 0.f; }
#pragma unroll
    for (int jb = 0; jb < 4; ++jb) {
        float ws_ = aSrc[f0 + jb * 16 + r];
        float wd_ = aDst[f0 + jb * 16 + r];
#pragma unroll
        for (int ja = 0; ja < 4; ++ja)
#pragma unroll
            for (int q = 0; q < 4; ++q) {
                ps[ja][q] += acc[ja][jb][q] * ws_;
                pd[ja][q] += acc[ja][jb][q] * wd_;
            }
    }
#pragma unroll
    for (int off = 1; off < 16; off <<= 1)
#pragma unroll
        for (int ja = 0; ja < 4; ++ja)
#pragma unroll
            for (int q = 0; q < 4; ++q) {
                ps[ja][q] += __shfl_xor(ps[ja][q], off, 64);
                pd[ja][q] += __shfl_xor(pd[ja][q], off, 64);
            }
    if (r == 0) {
        int Hh = F >> 6;
#pragma unroll
        for (int ja = 0; ja < 4; ++ja)
#pragma unroll
            for (int q = 0; q < 4; ++q) {
                int n = m0 + ja * 16 + g4 + q;
                if (n < Nn) {
                    a_s[(size_t)n * Hh + ft] = ps[ja][q];
                    a_d[(size_t)n * Hh + ft] = pd[ja][q];
                }
            }
    }
}

// ---------------- softmax + weighted aggregation (bucket CSR) ----------------
template<int H>
__global__ void aggregate_kernel(const unsigned short* __restrict__ Hb,
                                 const float* __restrict__ a_s, const float* __restrict__ a_d,
                                 const int* __restrict__ cnt, const int* __restrict__ bucket,
                                 const int* __restrict__ ovd, const int* __restrict__ ovs,
                                 const int* __restrict__ n_over,
                                 const float* __restrict__ bias,
                                 unsigned short* __restrict__ out, int Nn)
{
    constexpr int F = H * 64;
    constexpr int VEC = F / 64;
    __shared__ uint2 s_pk[4][64][H];
    int w = threadIdx.x >> 6;
    int node = blockIdx.x * 4 + w;
    int lane = threadIdx.x & 63;
    if (node >= Nn) return;
    int deg = cnt[node];

    float adn[H];
#pragma unroll
    for (int h = 0; h < H; ++h) adn[h] = a_d[(size_t)node * H + h];

    if (deg <= 64) {
        // -------- fast path: whole neighborhood in lane registers --------
        bool act = lane < deg;
        int sn = act ? bucket[(size_t)node * 64 + lane] : 0;
        float v[H];
        if (H == 4) {
            const f32x4 av = *reinterpret_cast<const f32x4*>(a_s + (size_t)sn * 4);
#pragma unroll
            for (int h = 0; h < 4; ++h) {
                float t = av[h] + adn[h];
                t = (t > 0.f) ? t : NEG_SLOPE * t;
                v[h] = act ? t : -1e30f;
            }
        } else {
            float t = a_s[sn] + adn[0];
            t = (t > 0.f) ? t : NEG_SLOPE * t;
            v[0] = act ? t : -1e30f;
        }
        float m[H], e[H], s[H];
#pragma unroll
        for (int h = 0; h < H; ++h) {
            m[h] = v[h];
#pragma unroll
            for (int off = 32; off >= 1; off >>= 1)
                m[h] = fmaxf(m[h], __shfl_xor(m[h], off, 64));
        }
#pragma unroll
        for (int h = 0; h < H; ++h) {
            e[h] = act ? __expf(v[h] - m[h]) : 0.f;
            s[h] = e[h];
#pragma unroll
            for (int off = 32; off >= 1; off >>= 1)
                s[h] += __shfl_xor(s[h], off, 64);
        }

        // stage packed (src, exp) per head in LDS (own-wave slice; no barrier needed)
#pragma unroll
        for (int h = 0; h < H; ++h)
            s_pk[w][lane][h] = make_uint2((unsigned int)sn, __float_as_uint(e[h]));
        asm volatile("s_waitcnt lgkmcnt(0)" ::: "memory");

        if (H == 4) {
            // 4 edges / iter: 16 lanes per edge, 16 ch/lane (2 x uint4)
            int laneq = lane & 15, qtr = lane >> 4, hd = laneq >> 2;
            float2 acc2[8];
#pragma unroll
            for (int k = 0; k < 8; ++k) acc2[k] = make_float2(0.f, 0.f);
            for (int j = 0; j < deg; j += 4) {
                uint2 pk = s_pk[w][j + qtr][hd];
                float ex = __uint_as_float(pk.y);
                const uint4* hp = reinterpret_cast<const uint4*>(Hb + (size_t)pk.x * 256 + laneq * 16);
                uint4 u0 = hp[0];
                uint4 u1 = hp[1];
                fma2(acc2[0], ex, u0.x); fma2(acc2[1], ex, u0.y);
                fma2(acc2[2], ex, u0.z); fma2(acc2[3], ex, u0.w);
                fma2(acc2[4], ex, u1.x); fma2(acc2[5], ex, u1.y);
                fma2(acc2[6], ex, u1.z); fma2(acc2[7], ex, u1.w);
            }
#pragma unroll
            for (int k = 0; k < 8; ++k) {
                acc2[k].x += __shfl_xor(acc2[k].x, 32, 64);
                acc2[k].y += __shfl_xor(acc2[k].y, 32, 64);
                acc2[k].x += __shfl_xor(acc2[k].x, 16, 64);
                acc2[k].y += __shfl_xor(acc2[k].y, 16, 64);
            }
            if (lane < 16) {
                int hd2 = lane >> 2;
                float sh = (hd2 == 0) ? s[0] : (hd2 == 1) ? s[1] : (hd2 == 2) ? s[2] : s[3];
                float inv = 1.f / (sh + 1e-16f);
                unsigned int pk8[8];
#pragma unroll
                for (int k = 0; k < 8; ++k) {
                    float t0 = acc2[k].x * inv + bias[lane * 16 + 2 * k];
                    float t1 = acc2[k].y * inv + bias[lane * 16 + 2 * k + 1];
                    unsigned int lo = f2bf(t0 > 0.f ? t0 : 0.f);
                    unsigned int hi = f2bf(t1 > 0.f ? t1 : 0.f);
                    pk8[k] = lo | (hi << 16);
                }
                uint4* op = reinterpret_cast<uint4*>(out + (size_t)node * 256 + lane * 16);
                op[0] = make_uint4(pk8[0], pk8[1], pk8[2], pk8[3]);
                op[1] = make_uint4(pk8[4], pk8[5], pk8[6], pk8[7]);
            }
        } else {
            // 8 edges / iter: 8 lanes per edge, 8 ch/lane (1 x uint4)
            int laneo = lane & 7, oct = lane >> 3;
            float2 acc2[4];
#pragma unroll
            for (int k = 0; k < 4; ++k) acc2[k] = make_float2(0.f, 0.f);
            for (int j = 0; j < deg; j += 8) {
                uint2 pk = s_pk[w][j + oct][0];
                float ex = __uint_as_float(pk.y);
                const uint4 u = *reinterpret_cast<const uint4*>(Hb + (size_t)pk.x * 64 + laneo * 8);
                fma2(acc2[0], ex, u.x); fma2(acc2[1], ex, u.y);
                fma2(acc2[2], ex, u.z); fma2(acc2[3], ex, u.w);
            }
#pragma unroll
            for (int k = 0; k < 4; ++k) {
                acc2[k].x += __shfl_xor(acc2[k].x, 32, 64);
                acc2[k].y += __shfl_xor(acc2[k].y, 32, 64);
                acc2[k].x += __shfl_xor(acc2[k].x, 16, 64);
                acc2[k].y += __shfl_xor(acc2[k].y, 16, 64);
                acc2[k].x += __shfl_xor(acc2[k].x, 8, 64);
                acc2[k].y += __shfl_xor(acc2[k].y, 8, 64);
            }
            if (lane < 8) {
                float inv = 1.f / (s[0] + 1e-16f);
                unsigned int pk4[4];
#pragma unroll
                for (int k = 0; k < 4; ++k) {
                    float t0 = acc2[k].x * inv + bias[lane * 8 + 2 * k];
                    float t1 = acc2[k].y * inv + bias[lane * 8 + 2 * k + 1];
                    unsigned int lo = f2bf(t0 > 0.f ? t0 : 0.f);
                    unsigned int hi = f2bf(t1 > 0.f ? t1 : 0.f);
                    pk4[k] = lo | (hi << 16);
                }
                *reinterpret_cast<uint4*>(out + (size_t)node * 64 + lane * 8) =
                    make_uint4(pk4[0], pk4[1], pk4[2], pk4[3]);
            }
        }
        return;
    }

    // -------- slow path (deg > 64): bucket (64 entries) + overflow list; exact --------
    int nov = *n_over;
    int head = (H == 1) ? 0 : (lane >> 4);
    float m[H], s[H];
#pragma unroll
    for (int h = 0; h < H; ++h) { m[h] = -1e30f; s[h] = 0.f; }
    {
        int sn = bucket[(size_t)node * 64 + lane];
#pragma unroll
        for (int h = 0; h < H; ++h) {
            float t = a_s[(size_t)sn * H + h] + adn[h];
            t = (t > 0.f) ? t : NEG_SLOPE * t;
            m[h] = fmaxf(m[h], t);
        }
    }
    for (int i = lane; i < nov; i += 64) {
        if (ovd[i] != node) continue;
        int sn = ovs[i];
#pragma unroll
        for (int h = 0; h < H; ++h) {
            float t = a_s[(size_t)sn * H + h] + adn[h];
            t = (t > 0.f) ? t : NEG_SLOPE * t;
            m[h] = fmaxf(m[h], t);
        }
    }
#pragma unroll
    for (int off = 32; off >= 1; off >>= 1)
#pragma unroll
        for (int h = 0; h < H; ++h) m[h] = fmaxf(m[h], __shfl_xor(m[h], off, 64));
    {
        int sn = bucket[(size_t)node * 64 + lane];
#pragma unroll
        for (int h = 0; h < H; ++h) {
            float t = a_s[(size_t)sn * H + h] + adn[h];
            t = (t > 0.f) ? t : NEG_SLOPE * t;
            s[h] += __expf(t - m[h]);
        }
    }
    for (int i = lane; i < nov; i += 64) {
        if (ovd[i] != node) continue;
        int sn = ovs[i];
#pragma unroll
        for (int h = 0; h < H; ++h) {
            float t = a_s[(size_t)sn * H + h] + adn[h];
            t = (t > 0.f) ? t : NEG_SLOPE * t;
            s[h] += __expf(t - m[h]);
        }
    }
#pragma unroll
    for (int off = 32; off >= 1; off >>= 1)
#pragma unroll
        for (int h = 0; h < H; ++h) s[h] += __shfl_xor(s[h], off, 64);

    float mh, sh, adh;
    if (H == 1) { mh = m[0]; sh = s[0]; adh = adn[0]; }
    else {
        mh  = (head == 0) ? m[0]   : (head == 1) ? m[1]   : (head == 2) ? m[2]   : m[3];
        sh  = (head == 0) ? s[0]   : (head == 1) ? s[1]   : (head == 2) ? s[2]   : s[3];
        adh = (head == 0) ? adn[0] : (head == 1) ? adn[1] : (head == 2) ? adn[2] : adn[3];
    }
    float inv = 1.f / (sh + 1e-16f);
    float acc[VEC];
#pragma unroll
    for (int k = 0; k < VEC; ++k) acc[k] = 0.f;
    for (int j = 0; j < 64; ++j) {
        int sn = bucket[(size_t)node * 64 + j];
        float t = a_s[(size_t)sn * H + head] + adh;
        t = (t > 0.f) ? t : NEG_SLOPE * t;
        float ex = __expf(t - mh);
        const unsigned short* hp = Hb + (size_t)sn * F + lane * VEC;
#pragma unroll
        for (int k = 0; k < VEC; ++k) acc[k] += ex * bf2f(hp[k]);
    }
    for (int i = 0; i < nov; ++i) {
        if (ovd[i] != node) continue;
        int sn = ovs[i];
        float t = a_s[(size_t)sn * H + head] + adh;
        t = (t > 0.f) ? t : NEG_SLOPE * t;
        float ex = __expf(t - mh);
        const unsigned short* hp = Hb + (size_t)sn * F + lane * VEC;
#pragma unroll
        for (int k = 0; k < VEC; ++k) acc[k] += ex * bf2f(hp[k]);
    }
#pragma unroll
    for (int k = 0; k < VEC; ++k) {
        int f = lane * VEC + k;
        float t = acc[k] * inv + bias[f];
        out[(size_t)node * F + f] = f2bf(t > 0.f ? t : 0.f);
    }
}

// ---------------- global mean pool (sums, bf16 input) ----------------
__global__ void pool_kernel(const unsigned short* __restrict__ x, const int* __restrict__ batch,
                            float* __restrict__ gsums, int Nn)
{
    int lane = threadIdx.x;        // blockDim = 64
    int n0 = blockIdx.x * 64;
    if (n0 >= Nn) return;
    int nend = min(n0 + 64, Nn);
    float acc = 0.f;
    int gcur = batch[n0];
    for (int n = n0; n < nend; ++n) {
        int g = batch[n];
        if (g != gcur) {
            atomicAdd(&gsums[gcur * 64 + lane], acc);
            acc = 0.f;
            gcur = g;
        }
        acc += bf2f(x[(size_t)n * 64 + lane]);
    }
    atomicAdd(&gsums[gcur * 64 + lane], acc);
}

// ---------------- final linear ----------------
__global__ void final_kernel(const float* __restrict__ gsums, const int* __restrict__ gcnt,
                             const float* __restrict__ linW, const float* __restrict__ linb,
                             float* __restrict__ out, int G)
{
    int t = threadIdx.x;
    if (t >= G * 10) return;
    int g = t / 10, j = t % 10;
    float cnt = (float)max(gcnt[g], 1);
    float acc = 0.f;
#pragma unroll
    for (int c = 0; c < 64; ++c) acc += gsums[g * 64 + c] * linW[j * 64 + c];
    out[g * 10 + j] = acc / cnt + linb[j];
}

extern "C" void kernel_launch(void* const* d_in, const int* in_sizes, int n_in,
                              void* d_out, int out_size, void* d_ws, size_t ws_size,
                              hipStream_t stream)
{
    const int*   x_ids    = (const int*)d_in[0];
    const float* degrees  = (const float*)d_in[1];
    const int*   edge_src = (const int*)d_in[2];
    const int*   edge_dst = (const int*)d_in[3];
    const int*   batch    = (const int*)d_in[4];
    const float* emb      = (const float*)d_in[5];
    const float* W1  = (const float*)d_in[6];
    const float* as1 = (const float*)d_in[7];
    const float* ad1 = (const float*)d_in[8];
    const float* b1  = (const float*)d_in[9];
    const float* W2  = (const float*)d_in[10];
    const float* as2 = (const float*)d_in[11];
    const float* ad2 = (const float*)d_in[12];
    const float* b2  = (const float*)d_in[13];
    const float* W3  = (const float*)d_in[14];
    const float* as3 = (const float*)d_in[15];
    const float* ad3 = (const float*)d_in[16];
    const float* b3  = (const float*)d_in[17];
    const float* linW = (const float*)d_in[18];
    const float* linb = (const float*)d_in[19];

    const int N  = in_sizes[0];
    const int E0 = in_sizes[2];
    const int E2 = E0 + N;
    const int G  = out_size / 10;
    const int nW1 = in_sizes[6], nW2 = in_sizes[10], nW3 = in_sizes[14];

    char* p = (char*)d_ws;
    size_t off = 0;
    auto take = [&](size_t bytes) {
        void* q = p + off;
        off = (off + bytes + 255) & ~(size_t)255;
        return q;
    };
    unsigned short* xA  = (unsigned short*)take((size_t)N * 256 * 2);
    unsigned short* xB  = (unsigned short*)take((size_t)N * 256 * 2);
    float* a_s     = (float*)take((size_t)N * 4 * 4);
    float* a_d     = (float*)take((size_t)N * 4 * 4);
    int*   cnt     = (int*)take((size_t)(N + 64) * 4);   // cnt[N] followed by n_over
    int*   n_over  = cnt + N;
    int*   bucket  = (int*)take((size_t)N * 64 * 4);
    int*   ovd     = (int*)take((size_t)E2 * 4);
    int*   ovs     = (int*)take((size_t)E2 * 4);
    float* gsums   = (float*)take((size_t)G * 64 * 4);
    int*   gcnt    = (int*)take((size_t)G * 4);
    unsigned short* w1b = (unsigned short*)take((size_t)nW1 * 2);
    unsigned short* w2b = (unsigned short*)take((size_t)nW2 * 2);
    unsigned short* w3b = (unsigned short*)take((size_t)nW3 * 2);

    hipMemsetAsync(cnt, 0, (size_t)(N + 1) * 4, stream);        // cnt + n_over
    hipMemsetAsync(gsums, 0, (size_t)G * 64 * 4, stream);

    const int nodeBlocks4 = (N + 3) / 4;
    const int edgeBlocks  = (E2 + 255) / 256;

    // prep mega-kernel block partition
    const int nWtot = nW1 + nW2 + nW3;
    const int bW = (nWtot + 255) / 256;
    const int bX = bW + nodeBlocks4;
    const int bH = bX + edgeBlocks;
    prep_kernel<<<bH + 1, 256, 0, stream>>>(W1, nW1, W2, nW2, W3, nW3, w1b, w2b, w3b,
                                            x_ids, degrees, emb, xA,
                                            edge_src, edge_dst, cnt, bucket, ovd, ovs, n_over,
                                            batch, gcnt,
                                            N, E0, E2, G, bW, bX, bH);

    const int mtiles = (N + 63) / 64;
    auto gemmBlocks = [&](int ftiles) { return (mtiles * ftiles + 3) / 4; };

    // ---- layer 1: 64 -> 4x64 concat ----
    gemm_mfma<<<gemmBlocks(4), 256, 0, stream>>>(xA, w1b, xB, as1, ad1, a_s, a_d, N, 64, 256);
    aggregate_kernel<4><<<nodeBlocks4, 256, 0, stream>>>(xB, a_s, a_d, cnt, bucket, ovd, ovs, n_over, b1, xA, N);
    // ---- layer 2: 256 -> 4x64 concat ----
    gemm_mfma<<<gemmBlocks(4), 256, 0, stream>>>(xA, w2b, xB, as2, ad2, a_s, a_d, N, 256, 256);
    aggregate_kernel<4><<<nodeBlocks4, 256, 0, stream>>>(xB, a_s, a_d, cnt, bucket, ovd, ovs, n_over, b2, xA, N);
    // ---- layer 3: 256 -> 1x64 (mean == identity) ----
    gemm_mfma<<<gemmBlocks(1), 256, 0, stream>>>(xA, w3b, xB, as3, ad3, a_s, a_d, N, 256, 64);
    aggregate_kernel<1><<<nodeBlocks4, 256, 0, stream>>>(xB, a_s, a_d, cnt, bucket, ovd, ovs, n_over, b3, xA, N);

    pool_kernel<<<(N + 63) / 64, 64, 0, stream>>>(xA, batch, gsums, N);
    final_kernel<<<1, ((G * 10 + 63) / 64) * 64, 0, stream>>>(gsums, gcnt, linW, linb, (float*)d_out, G);
}

// Round 7
// 331.794 us; speedup vs baseline: 3.6192x; 1.1216x over previous
//
#include <hip/hip_runtime.h>
#include <hip/hip_bf16.h>
#include <cstdint>

#define NEG_SLOPE 0.2f

typedef __bf16 bf16x8 __attribute__((ext_vector_type(8)));
typedef float  f32x4  __attribute__((ext_vector_type(4)));

__device__ __forceinline__ unsigned short f2bf(float f) {
    unsigned int u = __float_as_uint(f);
    u += 0x7fffu + ((u >> 16) & 1u);          // round-to-nearest-even
    return (unsigned short)(u >> 16);
}
__device__ __forceinline__ float bf2f(unsigned short u) {
    return __uint_as_float((unsigned int)u << 16);
}
__device__ __forceinline__ void fma2(float2& a, float ex, unsigned int u) {
    a.x = fmaf(ex, __uint_as_float(u << 16),         a.x);
    a.y = fmaf(ex, __uint_as_float(u & 0xffff0000u), a.y);
}

// ---------------- prep: f2bf(W) + build_x (+ self-loop CSR seed) + gcnt ----------------
__global__ void prep_kernel(const float* __restrict__ W1, int n1,
                            const float* __restrict__ W2, int n2,
                            const float* __restrict__ W3, int n3,
                            unsigned short* __restrict__ w1b, unsigned short* __restrict__ w2b,
                            unsigned short* __restrict__ w3b,
                            const int* __restrict__ ids, const float* __restrict__ degs,
                            const float* __restrict__ emb, unsigned short* __restrict__ x,
                            int* __restrict__ cnt, int* __restrict__ bucket,
                            int* __restrict__ n_over,
                            const int* __restrict__ batch, int* __restrict__ gcnt,
                            int Nn, int G, int bW, int bX)
{
    int b = blockIdx.x;
    if (b < bW) {
        int i = b * 256 + threadIdx.x;
        if (i < n1) w1b[i] = f2bf(W1[i]);
        int j = i - n1;
        if (j >= 0 && j < n2) w2b[j] = f2bf(W2[j]);
        int k = j - n2;
        if (k >= 0 && k < n3) w3b[k] = f2bf(W3[k]);
    } else if (b < bX) {
        int node = (b - bW) * 4 + (threadIdx.x >> 6);
        int lane = threadIdx.x & 63;
        if (node < Nn) {
            int id = ids[node];
            float v;
            if (lane < 62) v = emb[(size_t)id * 62 + lane];
            else           v = degs[node * 2 + (lane - 62)];
            x[(size_t)node * 64 + lane] = f2bf(v);
            if (lane == 0) {                       // self-loop seed: slot 0
                cnt[node] = 1;
                bucket[(size_t)node * 64] = node;
            }
        }
    } else {
        int g = threadIdx.x;
        if (g < G) {
            int lo0 = 0, hi = Nn;
            while (lo0 < hi) { int mid = (lo0 + hi) >> 1; if (batch[mid] < g) lo0 = mid + 1; else hi = mid; }
            int lo1 = lo0; hi = Nn;
            while (lo1 < hi) { int mid = (lo1 + hi) >> 1; if (batch[mid] < g + 1) lo1 = mid + 1; else hi = mid; }
            gcnt[g] = lo1 - lo0;
        }
        if (threadIdx.x == 255) *n_over = 0;
    }
}

// ---------------- fused: bf16 MFMA GEMM (64x64/wave) + edge scatter ----------------
// Blocks [0, gemmB): GEMM layer-1.  Blocks [gemmB, ...): 4-edge-ILP bucket scatter.
__global__ void gemm_scatter(const unsigned short* __restrict__ X, const unsigned short* __restrict__ Wb,
                             unsigned short* __restrict__ Hout,
                             const float* __restrict__ aSrc, const float* __restrict__ aDst,
                             float* __restrict__ a_s, float* __restrict__ a_d,
                             int Nn, int K, int F, int gemmB,
                             const int* __restrict__ esrc, const int* __restrict__ edst,
                             int* __restrict__ cnt, int* __restrict__ bucket,
                             int* __restrict__ ovd, int* __restrict__ ovs, int* __restrict__ n_over,
                             int E0)
{
    if (blockIdx.x >= gemmB) {
        int base = (blockIdx.x - gemmB) * 1024 + threadIdx.x;
        int sv[4], dv[4], pv[4];
        bool ok[4];
#pragma unroll
        for (int k = 0; k < 4; ++k) {
            int e = base + k * 256;
            ok[k] = (e < E0);
            if (ok[k]) { sv[k] = esrc[e]; dv[k] = edst[e]; }
        }
#pragma unroll
        for (int k = 0; k < 4; ++k)
            if (ok[k]) pv[k] = atomicAdd(&cnt[dv[k]], 1);
#pragma unroll
        for (int k = 0; k < 4; ++k) {
            if (ok[k]) {
                if (pv[k] < 64) bucket[(size_t)dv[k] * 64 + pv[k]] = sv[k];
                else {
                    int o = atomicAdd(n_over, 1);
                    ovd[o] = dv[k]; ovs[o] = sv[k];
                }
            }
        }
        return;
    }

    int wid  = (blockIdx.x * blockDim.x + threadIdx.x) >> 6;
    int lane = threadIdx.x & 63;
    int mtiles = (Nn + 63) >> 6;
    int ftiles = F >> 6;
    if (wid >= mtiles * ftiles) return;
    int ft = wid / mtiles;
    int mt = wid - ft * mtiles;
    int m0 = mt << 6, f0 = ft << 6;
    int r = lane & 15, g = lane >> 4, g4 = g << 2;

    const unsigned short* xrow[4];
#pragma unroll
    for (int ja = 0; ja < 4; ++ja) {
        int row = m0 + ja * 16 + r;
        if (row >= Nn) row = Nn - 1;
        xrow[ja] = X + (size_t)row * K + g * 8;
    }
    const unsigned short* wrow = Wb + (size_t)(f0 + r) * K + g * 8;
    const size_t wstep = (size_t)16 * K;

    f32x4 acc[4][4];
#pragma unroll
    for (int a = 0; a < 4; ++a)
#pragma unroll
        for (int b = 0; b < 4; ++b) acc[a][b] = f32x4{0.f, 0.f, 0.f, 0.f};

    for (int k0 = 0; k0 < K; k0 += 32) {
        bf16x8 av[4], bv[4];
#pragma unroll
        for (int ja = 0; ja < 4; ++ja) av[ja] = *reinterpret_cast<const bf16x8*>(xrow[ja] + k0);
#pragma unroll
        for (int jb = 0; jb < 4; ++jb) bv[jb] = *reinterpret_cast<const bf16x8*>(wrow + jb * wstep + k0);
#pragma unroll
        for (int ja = 0; ja < 4; ++ja)
#pragma unroll
            for (int jb = 0; jb < 4; ++jb)
                acc[ja][jb] = __builtin_amdgcn_mfma_f32_16x16x32_bf16(av[ja], bv[jb], acc[ja][jb], 0, 0, 0);
    }

#pragma unroll
    for (int ja = 0; ja < 4; ++ja)
#pragma unroll
        for (int q = 0; q < 4; ++q) {
            int row = m0 + ja * 16 + g4 + q;
            if (row < Nn) {
#pragma unroll
                for (int jb = 0; jb < 4; ++jb)
                    Hout[(size_t)row * F + f0 + jb * 16 + r] = f2bf(acc[ja][jb][q]);
            }
        }

    // fused attention-coefficient epilogue (fp32)
    float ps[4][4], pd[4][4];
#pragma unroll
    for (int ja = 0; ja < 4; ++ja)
#pragma unroll
        for (int q = 0; q < 4; ++q) { ps[ja][q] = 0.f; pd[ja][q] = 0.f; }
#pragma unroll
    for (int jb = 0; jb < 4; ++jb) {
        float ws_ = aSrc[f0 + jb * 16 + r];
        float wd_ = aDst[f0 + jb * 16 + r];
#pragma unroll
        for (int ja = 0; ja < 4; ++ja)
#pragma unroll
            for (int q = 0; q < 4; ++q) {
                ps[ja][q] += acc[ja][jb][q] * ws_;
                pd[ja][q] += acc[ja][jb][q] * wd_;
            }
    }
#pragma unroll
    for (int off = 1; off < 16; off <<= 1)
#pragma unroll
        for (int ja = 0; ja < 4; ++ja)
#pragma unroll
            for (int q = 0; q < 4; ++q) {
                ps[ja][q] += __shfl_xor(ps[ja][q], off, 64);
                pd[ja][q] += __shfl_xor(pd[ja][q], off, 64);
            }
    if (r == 0) {
        int Hh = F >> 6;
#pragma unroll
        for (int ja = 0; ja < 4; ++ja)
#pragma unroll
            for (int q = 0; q < 4; ++q) {
                int n = m0 + ja * 16 + g4 + q;
                if (n < Nn) {
                    a_s[(size_t)n * Hh + ft] = ps[ja][q];
                    a_d[(size_t)n * Hh + ft] = pd[ja][q];
                }
            }
    }
}

// ---------------- plain GEMM wrapper (layers 2,3) ----------------
__global__ void gemm_mfma(const unsigned short* __restrict__ X, const unsigned short* __restrict__ Wb,
                          unsigned short* __restrict__ Hout,
                          const float* __restrict__ aSrc, const float* __restrict__ aDst,
                          float* __restrict__ a_s, float* __restrict__ a_d,
                          int Nn, int K, int F)
{
    int wid  = (blockIdx.x * blockDim.x + threadIdx.x) >> 6;
    int lane = threadIdx.x & 63;
    int mtiles = (Nn + 63) >> 6;
    int ftiles = F >> 6;
    if (wid >= mtiles * ftiles) return;
    int ft = wid / mtiles;
    int mt = wid - ft * mtiles;
    int m0 = mt << 6, f0 = ft << 6;
    int r = lane & 15, g = lane >> 4, g4 = g << 2;

    const unsigned short* xrow[4];
#pragma unroll
    for (int ja = 0; ja < 4; ++ja) {
        int row = m0 + ja * 16 + r;
        if (row >= Nn) row = Nn - 1;
        xrow[ja] = X + (size_t)row * K + g * 8;
    }
    const unsigned short* wrow = Wb + (size_t)(f0 + r) * K + g * 8;
    const size_t wstep = (size_t)16 * K;

    f32x4 acc[4][4];
#pragma unroll
    for (int a = 0; a < 4; ++a)
#pragma unroll
        for (int b = 0; b < 4; ++b) acc[a][b] = f32x4{0.f, 0.f, 0.f, 0.f};

    for (int k0 = 0; k0 < K; k0 += 32) {
        bf16x8 av[4], bv[4];
#pragma unroll
        for (int ja = 0; ja < 4; ++ja) av[ja] = *reinterpret_cast<const bf16x8*>(xrow[ja] + k0);
#pragma unroll
        for (int jb = 0; jb < 4; ++jb) bv[jb] = *reinterpret_cast<const bf16x8*>(wrow + jb * wstep + k0);
#pragma unroll
        for (int ja = 0; ja < 4; ++ja)
#pragma unroll
            for (int jb = 0; jb < 4; ++jb)
                acc[ja][jb] = __builtin_amdgcn_mfma_f32_16x16x32_bf16(av[ja], bv[jb], acc[ja][jb], 0, 0, 0);
    }

#pragma unroll
    for (int ja = 0; ja < 4; ++ja)
#pragma unroll
        for (int q = 0; q < 4; ++q) {
            int row = m0 + ja * 16 + g4 + q;
            if (row < Nn) {
#pragma unroll
                for (int jb = 0; jb < 4; ++jb)
                    Hout[(size_t)row * F + f0 + jb * 16 + r] = f2bf(acc[ja][jb][q]);
            }
        }

    float ps[4][4], pd[4][4];
#pragma unroll
    for (int ja = 0; ja < 4; ++ja)
#pragma unroll
        for (int q = 0; q < 4; ++q) { ps[ja][q] = 0.f; pd[ja][q] = 0.f; }
#pragma unroll
    for (int jb = 0; jb < 4; ++jb) {
        float ws_ = aSrc[f0 + jb * 16 + r];
        float wd_ = aDst[f0 + jb * 16 + r];
#pragma unroll
        for (int ja = 0; ja < 4; ++ja)
#pragma unroll
            for (int q = 0; q < 4; ++q) {
                ps[ja][q] += acc[ja][jb][q] * ws_;
                pd[ja][q] += acc[ja][jb][q] * wd_;
            }
    }
#pragma unroll
    for (int off = 1; off < 16; off <<= 1)
#pragma unroll
        for (int ja = 0; ja < 4; ++ja)
#pragma unroll
            for (int q = 0; q < 4; ++q) {
                ps[ja][q] += __shfl_xor(ps[ja][q], off, 64);
                pd[ja][q] += __shfl_xor(pd[ja][q], off, 64);
            }
    if (r == 0) {
        int Hh = F >> 6;
#pragma unroll
        for (int ja = 0; ja < 4; ++ja)
#pragma unroll
            for (int q = 0; q < 4; ++q) {
                int n = m0 + ja * 16 + g4 + q;
                if (n < Nn) {
                    a_s[(size_t)n * Hh + ft] = ps[ja][q];
                    a_d[(size_t)n * Hh + ft] = pd[ja][q];
                }
            }
    }
}

// ---------------- softmax + weighted aggregation (bucket CSR) ----------------
template<int H>
__global__ void aggregate_kernel(const unsigned short* __restrict__ Hb,
                                 const float* __restrict__ a_s, const float* __restrict__ a_d,
                                 const int* __restrict__ cnt, const int* __restrict__ bucket,
                                 const int* __restrict__ ovd, const int* __restrict__ ovs,
                                 const int* __restrict__ n_over,
                                 const float* __restrict__ bias,
                                 unsigned short* __restrict__ out, int Nn)
{
    constexpr int F = H * 64;
    constexpr int VEC = F / 64;
    __shared__ uint2 s_pk[4][64][H];
    int w = threadIdx.x >> 6;
    int node = blockIdx.x * 4 + w;
    int lane = threadIdx.x & 63;
    if (node >= Nn) return;
    int deg = cnt[node];

    float adn[H];
#pragma unroll
    for (int h = 0; h < H; ++h) adn[h] = a_d[(size_t)node * H + h];

    if (deg <= 64) {
        // -------- fast path: whole neighborhood in lane registers --------
        bool act = lane < deg;
        int sn = act ? bucket[(size_t)node * 64 + lane] : 0;
        float v[H];
        if (H == 4) {
            const f32x4 av = *reinterpret_cast<const f32x4*>(a_s + (size_t)sn * 4);
#pragma unroll
            for (int h = 0; h < 4; ++h) {
                float t = av[h] + adn[h];
                t = (t > 0.f) ? t : NEG_SLOPE * t;
                v[h] = act ? t : -1e30f;
            }
        } else {
            float t = a_s[sn] + adn[0];
            t = (t > 0.f) ? t : NEG_SLOPE * t;
            v[0] = act ? t : -1e30f;
        }
        float m[H], e[H], s[H];
#pragma unroll
        for (int h = 0; h < H; ++h) {
            m[h] = v[h];
#pragma unroll
            for (int off = 32; off >= 1; off >>= 1)
                m[h] = fmaxf(m[h], __shfl_xor(m[h], off, 64));
        }
#pragma unroll
        for (int h = 0; h < H; ++h) {
            e[h] = act ? __expf(v[h] - m[h]) : 0.f;
            s[h] = e[h];
#pragma unroll
            for (int off = 32; off >= 1; off >>= 1)
                s[h] += __shfl_xor(s[h], off, 64);
        }

        // stage packed (src, exp) per head in LDS (own-wave slice; no barrier needed)
#pragma unroll
        for (int h = 0; h < H; ++h)
            s_pk[w][lane][h] = make_uint2((unsigned int)sn, __float_as_uint(e[h]));
        asm volatile("s_waitcnt lgkmcnt(0)" ::: "memory");

        if (H == 4) {
            // 4 edges / iter: 16 lanes per edge, 16 ch/lane (2 x uint4)
            int laneq = lane & 15, qtr = lane >> 4, hd = laneq >> 2;
            float2 acc2[8];
#pragma unroll
            for (int k = 0; k < 8; ++k) acc2[k] = make_float2(0.f, 0.f);
            for (int j = 0; j < deg; j += 4) {
                uint2 pk = s_pk[w][j + qtr][hd];
                float ex = __uint_as_float(pk.y);
                const uint4* hp = reinterpret_cast<const uint4*>(Hb + (size_t)pk.x * 256 + laneq * 16);
                uint4 u0 = hp[0];
                uint4 u1 = hp[1];
                fma2(acc2[0], ex, u0.x); fma2(acc2[1], ex, u0.y);
                fma2(acc2[2], ex, u0.z); fma2(acc2[3], ex, u0.w);
                fma2(acc2[4], ex, u1.x); fma2(acc2[5], ex, u1.y);
                fma2(acc2[6], ex, u1.z); fma2(acc2[7], ex, u1.w);
            }
#pragma unroll
            for (int k = 0; k < 8; ++k) {
                acc2[k].x += __shfl_xor(acc2[k].x, 32, 64);
                acc2[k].y += __shfl_xor(acc2[k].y, 32, 64);
                acc2[k].x += __shfl_xor(acc2[k].x, 16, 64);
                acc2[k].y += __shfl_xor(acc2[k].y, 16, 64);
            }
            if (lane < 16) {
                int hd2 = lane >> 2;
                float sh = (hd2 == 0) ? s[0] : (hd2 == 1) ? s[1] : (hd2 == 2) ? s[2] : s[3];
                float inv = 1.f / (sh + 1e-16f);
                unsigned int pk8[8];
#pragma unroll
                for (int k = 0; k < 8; ++k) {
                    float t0 = acc2[k].x * inv + bias[lane * 16 + 2 * k];
                    float t1 = acc2[k].y * inv + bias[lane * 16 + 2 * k + 1];
                    unsigned int lo = f2bf(t0 > 0.f ? t0 : 0.f);
                    unsigned int hi = f2bf(t1 > 0.f ? t1 : 0.f);
                    pk8[k] = lo | (hi << 16);
                }
                uint4* op = reinterpret_cast<uint4*>(out + (size_t)node * 256 + lane * 16);
                op[0] = make_uint4(pk8[0], pk8[1], pk8[2], pk8[3]);
                op[1] = make_uint4(pk8[4], pk8[5], pk8[6], pk8[7]);
            }
        } else {
            // 8 edges / iter: 8 lanes per edge, 8 ch/lane (1 x uint4)
            int laneo = lane & 7, oct = lane >> 3;
            float2 acc2[4];
#pragma unroll
            for (int k = 0; k < 4; ++k) acc2[k] = make_float2(0.f, 0.f);
            for (int j = 0; j < deg; j += 8) {
                uint2 pk = s_pk[w][j + oct][0];
                float ex = __uint_as_float(pk.y);
                const uint4 u = *reinterpret_cast<const uint4*>(Hb + (size_t)pk.x * 64 + laneo * 8);
                fma2(acc2[0], ex, u.x); fma2(acc2[1], ex, u.y);
                fma2(acc2[2], ex, u.z); fma2(acc2[3], ex, u.w);
            }
#pragma unroll
            for (int k = 0; k < 4; ++k) {
                acc2[k].x += __shfl_xor(acc2[k].x, 32, 64);
                acc2[k].y += __shfl_xor(acc2[k].y, 32, 64);
                acc2[k].x += __shfl_xor(acc2[k].x, 16, 64);
                acc2[k].y += __shfl_xor(acc2[k].y, 16, 64);
                acc2[k].x += __shfl_xor(acc2[k].x, 8, 64);
                acc2[k].y += __shfl_xor(acc2[k].y, 8, 64);
            }
            if (lane < 8) {
                float inv = 1.f / (s[0] + 1e-16f);
                unsigned int pk4[4];
#pragma unroll
                for (int k = 0; k < 4; ++k) {
                    float t0 = acc2[k].x * inv + bias[lane * 8 + 2 * k];
                    float t1 = acc2[k].y * inv + bias[lane * 8 + 2 * k + 1];
                    unsigned int lo = f2bf(t0 > 0.f ? t0 : 0.f);
                    unsigned int hi = f2bf(t1 > 0.f ? t1 : 0.f);
                    pk4[k] = lo | (hi << 16);
                }
                *reinterpret_cast<uint4*>(out + (size_t)node * 64 + lane * 8) =
                    make_uint4(pk4[0], pk4[1], pk4[2], pk4[3]);
            }
        }
        return;
    }

    // -------- slow path (deg > 64): bucket (64 entries) + overflow list; exact --------
    int nov = *n_over;
    int head = (H == 1) ? 0 : (lane >> 4);
    float m[H], s[H];
#pragma unroll
    for (int h = 0; h < H; ++h) { m[h] = -1e30f; s[h] = 0.f; }
    {
        int sn = bucket[(size_t)node * 64 + lane];
#pragma unroll
        for (int h = 0; h < H; ++h) {
            float t = a_s[(size_t)sn * H + h] + adn[h];
            t = (t > 0.f) ? t : NEG_SLOPE * t;
            m[h] = fmaxf(m[h], t);
        }
    }
    for (int i = lane; i < nov; i += 64) {
        if (ovd[i] != node) continue;
        int sn = ovs[i];
#pragma unroll
        for (int h = 0; h < H; ++h) {
            float t = a_s[(size_t)sn * H + h] + adn[h];
            t = (t > 0.f) ? t : NEG_SLOPE * t;
            m[h] = fmaxf(m[h], t);
        }
    }
#pragma unroll
    for (int off = 32; off >= 1; off >>= 1)
#pragma unroll
        for (int h = 0; h < H; ++h) m[h] = fmaxf(m[h], __shfl_xor(m[h], off, 64));
    {
        int sn = bucket[(size_t)node * 64 + lane];
#pragma unroll
        for (int h = 0; h < H; ++h) {
            float t = a_s[(size_t)sn * H + h] + adn[h];
            t = (t > 0.f) ? t : NEG_SLOPE * t;
            s[h] += __expf(t - m[h]);
        }
    }
    for (int i = lane; i < nov; i += 64) {
        if (ovd[i] != node) continue;
        int sn = ovs[i];
#pragma unroll
        for (int h = 0; h < H; ++h) {
            float t = a_s[(size_t)sn * H + h] + adn[h];
            t = (t > 0.f) ? t : NEG_SLOPE * t;
            s[h] += __expf(t - m[h]);
        }
    }
#pragma unroll
    for (int off = 32; off >= 1; off >>= 1)
#pragma unroll
        for (int h = 0; h < H; ++h) s[h] += __shfl_xor(s[h], off, 64);

    float mh, sh, adh;
    if (H == 1) { mh = m[0]; sh = s[0]; adh = adn[0]; }
    else {
        mh  = (head == 0) ? m[0]   : (head == 1) ? m[1]   : (head == 2) ? m[2]   : m[3];
        sh  = (head == 0) ? s[0]   : (head == 1) ? s[1]   : (head == 2) ? s[2]   : s[3];
        adh = (head == 0) ? adn[0] : (head == 1) ? adn[1] : (head == 2) ? adn[2] : adn[3];
    }
    float inv = 1.f / (sh + 1e-16f);
    float acc[VEC];
#pragma unroll
    for (int k = 0; k < VEC; ++k) acc[k] = 0.f;
    for (int j = 0; j < 64; ++j) {
        int sn = bucket[(size_t)node * 64 + j];
        float t = a_s[(size_t)sn * H + head] + adh;
        t = (t > 0.f) ? t : NEG_SLOPE * t;
        float ex = __expf(t - mh);
        const unsigned short* hp = Hb + (size_t)sn * F + lane * VEC;
#pragma unroll
        for (int k = 0; k < VEC; ++k) acc[k] += ex * bf2f(hp[k]);
    }
    for (int i = 0; i < nov; ++i) {
        if (ovd[i] != node) continue;
        int sn = ovs[i];
        float t = a_s[(size_t)sn * H + head] + adh;
        t = (t > 0.f) ? t : NEG_SLOPE * t;
        float ex = __expf(t - mh);
        const unsigned short* hp = Hb + (size_t)sn * F + lane * VEC;
#pragma unroll
        for (int k = 0; k < VEC; ++k) acc[k] += ex * bf2f(hp[k]);
    }
#pragma unroll
    for (int k = 0; k < VEC; ++k) {
        int f = lane * VEC + k;
        float t = acc[k] * inv + bias[f];
        out[(size_t)node * F + f] = f2bf(t > 0.f ? t : 0.f);
    }
}

// ---------------- global mean pool (sums, bf16 input) ----------------
__global__ void pool_kernel(const unsigned short* __restrict__ x, const int* __restrict__ batch,
                            float* __restrict__ gsums, int Nn)
{
    int lane = threadIdx.x;        // blockDim = 64
    int n0 = blockIdx.x * 64;
    if (n0 >= Nn) return;
    int nend = min(n0 + 64, Nn);
    float acc = 0.f;
    int gcur = batch[n0];
    for (int n = n0; n < nend; ++n) {
        int g = batch[n];
        if (g != gcur) {
            atomicAdd(&gsums[gcur * 64 + lane], acc);
            acc = 0.f;
            gcur = g;
        }
        acc += bf2f(x[(size_t)n * 64 + lane]);
    }
    atomicAdd(&gsums[gcur * 64 + lane], acc);
}

// ---------------- final linear ----------------
__global__ void final_kernel(const float* __restrict__ gsums, const int* __restrict__ gcnt,
                             const float* __restrict__ linW, const float* __restrict__ linb,
                             float* __restrict__ out, int G)
{
    int t = threadIdx.x;
    if (t >= G * 10) return;
    int g = t / 10, j = t % 10;
    float cnt = (float)max(gcnt[g], 1);
    float acc = 0.f;
#pragma unroll
    for (int c = 0; c < 64; ++c) acc += gsums[g * 64 + c] * linW[j * 64 + c];
    out[g * 10 + j] = acc / cnt + linb[j];
}

extern "C" void kernel_launch(void* const* d_in, const int* in_sizes, int n_in,
                              void* d_out, int out_size, void* d_ws, size_t ws_size,
                              hipStream_t stream)
{
    const int*   x_ids    = (const int*)d_in[0];
    const float* degrees  = (const float*)d_in[1];
    const int*   edge_src = (const int*)d_in[2];
    const int*   edge_dst = (const int*)d_in[3];
    const int*   batch    = (const int*)d_in[4];
    const float* emb      = (const float*)d_in[5];
    const float* W1  = (const float*)d_in[6];
    const float* as1 = (const float*)d_in[7];
    const float* ad1 = (const float*)d_in[8];
    const float* b1  = (const float*)d_in[9];
    const float* W2  = (const float*)d_in[10];
    const float* as2 = (const float*)d_in[11];
    const float* ad2 = (const float*)d_in[12];
    const float* b2  = (const float*)d_in[13];
    const float* W3  = (const float*)d_in[14];
    const float* as3 = (const float*)d_in[15];
    const float* ad3 = (const float*)d_in[16];
    const float* b3  = (const float*)d_in[17];
    const float* linW = (const float*)d_in[18];
    const float* linb = (const float*)d_in[19];

    const int N  = in_sizes[0];
    const int E0 = in_sizes[2];
    const int E2 = E0 + N;
    const int G  = out_size / 10;
    const int nW1 = in_sizes[6], nW2 = in_sizes[10], nW3 = in_sizes[14];

    char* p = (char*)d_ws;
    size_t off = 0;
    auto take = [&](size_t bytes) {
        void* q = p + off;
        off = (off + bytes + 255) & ~(size_t)255;
        return q;
    };
    unsigned short* xA  = (unsigned short*)take((size_t)N * 256 * 2);
    unsigned short* xB  = (unsigned short*)take((size_t)N * 256 * 2);
    float* a_s     = (float*)take((size_t)N * 4 * 4);
    float* a_d     = (float*)take((size_t)N * 4 * 4);
    int*   cnt     = (int*)take((size_t)(N + 64) * 4);   // cnt[N] followed by n_over
    int*   n_over  = cnt + N;
    int*   bucket  = (int*)take((size_t)N * 64 * 4);
    int*   ovd     = (int*)take((size_t)E2 * 4);
    int*   ovs     = (int*)take((size_t)E2 * 4);
    float* gsums   = (float*)take((size_t)G * 64 * 4);
    int*   gcnt    = (int*)take((size_t)G * 4);
    unsigned short* w1b = (unsigned short*)take((size_t)nW1 * 2);
    unsigned short* w2b = (unsigned short*)take((size_t)nW2 * 2);
    unsigned short* w3b = (unsigned short*)take((size_t)nW3 * 2);

    hipMemsetAsync(gsums, 0, (size_t)G * 64 * 4, stream);

    const int nodeBlocks4 = (N + 3) / 4;

    // prep block partition
    const int nWtot = nW1 + nW2 + nW3;
    const int bW = (nWtot + 255) / 256;
    const int bX = bW + nodeBlocks4;
    prep_kernel<<<bX + 1, 256, 0, stream>>>(W1, nW1, W2, nW2, W3, nW3, w1b, w2b, w3b,
                                            x_ids, degrees, emb, xA,
                                            cnt, bucket, n_over, batch, gcnt,
                                            N, G, bW, bX);

    const int mtiles = (N + 63) / 64;
    auto gemmBlocks = [&](int ftiles) { return (mtiles * ftiles + 3) / 4; };

    // ---- layer 1 (fused with edge scatter): 64 -> 4x64 concat ----
    const int gemmB1   = gemmBlocks(4);
    const int scatterB = (E0 + 1023) / 1024;
    gemm_scatter<<<gemmB1 + scatterB, 256, 0, stream>>>(xA, w1b, xB, as1, ad1, a_s, a_d,
                                                        N, 64, 256, gemmB1,
                                                        edge_src, edge_dst, cnt, bucket,
                                                        ovd, ovs, n_over, E0);
    aggregate_kernel<4><<<nodeBlocks4, 256, 0, stream>>>(xB, a_s, a_d, cnt, bucket, ovd, ovs, n_over, b1, xA, N);
    // ---- layer 2: 256 -> 4x64 concat ----
    gemm_mfma<<<gemmBlocks(4), 256, 0, stream>>>(xA, w2b, xB, as2, ad2, a_s, a_d, N, 256, 256);
    aggregate_kernel<4><<<nodeBlocks4, 256, 0, stream>>>(xB, a_s, a_d, cnt, bucket, ovd, ovs, n_over, b2, xA, N);
    // ---- layer 3: 256 -> 1x64 (mean == identity) ----
    gemm_mfma<<<gemmBlocks(1), 256, 0, stream>>>(xA, w3b, xB, as3, ad3, a_s, a_d, N, 256, 64);
    aggregate_kernel<1><<<nodeBlocks4, 256, 0, stream>>>(xB, a_s, a_d, cnt, bucket, ovd, ovs, n_over, b3, xA, N);

    pool_kernel<<<(N + 63) / 64, 64, 0, stream>>>(xA, batch, gsums, N);
    final_kernel<<<1, ((G * 10 + 63) / 64) * 64, 0, stream>>>(gsums, gcnt, linW, linb, (float*)d_out, G);
}

// Round 8
// 328.331 us; speedup vs baseline: 3.6574x; 1.0105x over previous
//
#include <hip/hip_runtime.h>
#include <hip/hip_bf16.h>
#include <cstdint>

#define NEG_SLOPE 0.2f

typedef __bf16 bf16x8 __attribute__((ext_vector_type(8)));
typedef float  f32x4  __attribute__((ext_vector_type(4)));

__device__ __forceinline__ unsigned short f2bf(float f) {
    unsigned int u = __float_as_uint(f);
    u += 0x7fffu + ((u >> 16) & 1u);          // round-to-nearest-even
    return (unsigned short)(u >> 16);
}
__device__ __forceinline__ float bf2f(unsigned short u) {
    return __uint_as_float((unsigned int)u << 16);
}
__device__ __forceinline__ void fma2(float2& a, float ex, unsigned int u) {
    a.x = fmaf(ex, __uint_as_float(u << 16),         a.x);
    a.y = fmaf(ex, __uint_as_float(u & 0xffff0000u), a.y);
}

// ---------------- prep: f2bf(W) + build_x (+ self-loop CSR seed) + gcnt ----------------
__global__ void prep_kernel(const float* __restrict__ W1, int n1,
                            const float* __restrict__ W2, int n2,
                            const float* __restrict__ W3, int n3,
                            unsigned short* __restrict__ w1b, unsigned short* __restrict__ w2b,
                            unsigned short* __restrict__ w3b,
                            const int* __restrict__ ids, const float* __restrict__ degs,
                            const float* __restrict__ emb, unsigned short* __restrict__ x,
                            int* __restrict__ cnt, int* __restrict__ bucket,
                            int* __restrict__ n_over,
                            const int* __restrict__ batch, int* __restrict__ gcnt,
                            int Nn, int G, int bW, int bX)
{
    int b = blockIdx.x;
    if (b < bW) {
        int i = b * 256 + threadIdx.x;
        if (i < n1) w1b[i] = f2bf(W1[i]);
        int j = i - n1;
        if (j >= 0 && j < n2) w2b[j] = f2bf(W2[j]);
        int k = j - n2;
        if (k >= 0 && k < n3) w3b[k] = f2bf(W3[k]);
    } else if (b < bX) {
        int node = (b - bW) * 4 + (threadIdx.x >> 6);
        int lane = threadIdx.x & 63;
        if (node < Nn) {
            int id = ids[node];
            float v;
            if (lane < 62) v = emb[(size_t)id * 62 + lane];
            else           v = degs[node * 2 + (lane - 62)];
            x[(size_t)node * 64 + lane] = f2bf(v);
            if (lane == 0) {                       // self-loop seed: slot 0
                cnt[node] = 1;
                bucket[(size_t)node * 64] = node;
            }
        }
    } else {
        int g = threadIdx.x;
        if (g < G) {
            int lo0 = 0, hi = Nn;
            while (lo0 < hi) { int mid = (lo0 + hi) >> 1; if (batch[mid] < g) lo0 = mid + 1; else hi = mid; }
            int lo1 = lo0; hi = Nn;
            while (lo1 < hi) { int mid = (lo1 + hi) >> 1; if (batch[mid] < g + 1) lo1 = mid + 1; else hi = mid; }
            gcnt[g] = lo1 - lo0;
        }
        if (threadIdx.x == 255) *n_over = 0;
    }
}

// ---------------- fused: bf16 MFMA GEMM (64x64/wave) + edge scatter ----------------
__global__ void gemm_scatter(const unsigned short* __restrict__ X, const unsigned short* __restrict__ Wb,
                             unsigned short* __restrict__ Hout,
                             const float* __restrict__ aSrc, const float* __restrict__ aDst,
                             float* __restrict__ a_s, float* __restrict__ a_d,
                             int Nn, int K, int F, int gemmB,
                             const int* __restrict__ esrc, const int* __restrict__ edst,
                             int* __restrict__ cnt, int* __restrict__ bucket,
                             int* __restrict__ ovd, int* __restrict__ ovs, int* __restrict__ n_over,
                             int E0)
{
    if (blockIdx.x >= gemmB) {
        int base = (blockIdx.x - gemmB) * 1024 + threadIdx.x;
        int sv[4], dv[4], pv[4];
        bool ok[4];
#pragma unroll
        for (int k = 0; k < 4; ++k) {
            int e = base + k * 256;
            ok[k] = (e < E0);
            if (ok[k]) { sv[k] = esrc[e]; dv[k] = edst[e]; }
        }
#pragma unroll
        for (int k = 0; k < 4; ++k)
            if (ok[k]) pv[k] = atomicAdd(&cnt[dv[k]], 1);
#pragma unroll
        for (int k = 0; k < 4; ++k) {
            if (ok[k]) {
                if (pv[k] < 64) bucket[(size_t)dv[k] * 64 + pv[k]] = sv[k];
                else {
                    int o = atomicAdd(n_over, 1);
                    ovd[o] = dv[k]; ovs[o] = sv[k];
                }
            }
        }
        return;
    }

    int wid  = (blockIdx.x * blockDim.x + threadIdx.x) >> 6;
    int lane = threadIdx.x & 63;
    int mtiles = (Nn + 63) >> 6;
    int ftiles = F >> 6;
    if (wid >= mtiles * ftiles) return;
    int ft = wid % ftiles;              // block-local f-tiles: 4 waves of a block share one X-tile
    int mt = wid / ftiles;
    int m0 = mt << 6, f0 = ft << 6;
    int r = lane & 15, g = lane >> 4, g4 = g << 2;

    const unsigned short* xrow[4];
#pragma unroll
    for (int ja = 0; ja < 4; ++ja) {
        int row = m0 + ja * 16 + r;
        if (row >= Nn) row = Nn - 1;
        xrow[ja] = X + (size_t)row * K + g * 8;
    }
    const unsigned short* wrow = Wb + (size_t)(f0 + r) * K + g * 8;
    const size_t wstep = (size_t)16 * K;

    f32x4 acc[4][4];
#pragma unroll
    for (int a = 0; a < 4; ++a)
#pragma unroll
        for (int b = 0; b < 4; ++b) acc[a][b] = f32x4{0.f, 0.f, 0.f, 0.f};

    for (int k0 = 0; k0 < K; k0 += 32) {
        bf16x8 av[4], bv[4];
#pragma unroll
        for (int ja = 0; ja < 4; ++ja) av[ja] = *reinterpret_cast<const bf16x8*>(xrow[ja] + k0);
#pragma unroll
        for (int jb = 0; jb < 4; ++jb) bv[jb] = *reinterpret_cast<const bf16x8*>(wrow + jb * wstep + k0);
#pragma unroll
        for (int ja = 0; ja < 4; ++ja)
#pragma unroll
            for (int jb = 0; jb < 4; ++jb)
                acc[ja][jb] = __builtin_amdgcn_mfma_f32_16x16x32_bf16(av[ja], bv[jb], acc[ja][jb], 0, 0, 0);
    }

#pragma unroll
    for (int ja = 0; ja < 4; ++ja)
#pragma unroll
        for (int q = 0; q < 4; ++q) {
            int row = m0 + ja * 16 + g4 + q;
            if (row < Nn) {
#pragma unroll
                for (int jb = 0; jb < 4; ++jb)
                    Hout[(size_t)row * F + f0 + jb * 16 + r] = f2bf(acc[ja][jb][q]);
            }
        }

    float ps[4][4], pd[4][4];
#pragma unroll
    for (int ja = 0; ja < 4; ++ja)
#pragma unroll
        for (int q = 0; q < 4; ++q) { ps[ja][q] = 0.f; pd[ja][q] = 0.f; }
#pragma unroll
    for (int jb = 0; jb < 4; ++jb) {
        float ws_ = aSrc[f0 + jb * 16 + r];
        float wd_ = aDst[f0 + jb * 16 + r];
#pragma unroll
        for (int ja = 0; ja < 4; ++ja)
#pragma unroll
            for (int q = 0; q < 4; ++q) {
                ps[ja][q] += acc[ja][jb][q] * ws_;
                pd[ja][q] += acc[ja][jb][q] * wd_;
            }
    }
#pragma unroll
    for (int off = 1; off < 16; off <<= 1)
#pragma unroll
        for (int ja = 0; ja < 4; ++ja)
#pragma unroll
            for (int q = 0; q < 4; ++q) {
                ps[ja][q] += __shfl_xor(ps[ja][q], off, 64);
                pd[ja][q] += __shfl_xor(pd[ja][q], off, 64);
            }
    if (r == 0) {
        int Hh = F >> 6;
#pragma unroll
        for (int ja = 0; ja < 4; ++ja)
#pragma unroll
            for (int q = 0; q < 4; ++q) {
                int n = m0 + ja * 16 + g4 + q;
                if (n < Nn) {
                    a_s[(size_t)n * Hh + ft] = ps[ja][q];
                    a_d[(size_t)n * Hh + ft] = pd[ja][q];
                }
            }
    }
}

// ---------------- plain GEMM (layers 2,3) ----------------
__global__ void gemm_mfma(const unsigned short* __restrict__ X, const unsigned short* __restrict__ Wb,
                          unsigned short* __restrict__ Hout,
                          const float* __restrict__ aSrc, const float* __restrict__ aDst,
                          float* __restrict__ a_s, float* __restrict__ a_d,
                          int Nn, int K, int F)
{
    int wid  = (blockIdx.x * blockDim.x + threadIdx.x) >> 6;
    int lane = threadIdx.x & 63;
    int mtiles = (Nn + 63) >> 6;
    int ftiles = F >> 6;
    if (wid >= mtiles * ftiles) return;
    int ft = wid % ftiles;              // block-local f-tiles: X-tile reuse within block
    int mt = wid / ftiles;
    int m0 = mt << 6, f0 = ft << 6;
    int r = lane & 15, g = lane >> 4, g4 = g << 2;

    const unsigned short* xrow[4];
#pragma unroll
    for (int ja = 0; ja < 4; ++ja) {
        int row = m0 + ja * 16 + r;
        if (row >= Nn) row = Nn - 1;
        xrow[ja] = X + (size_t)row * K + g * 8;
    }
    const unsigned short* wrow = Wb + (size_t)(f0 + r) * K + g * 8;
    const size_t wstep = (size_t)16 * K;

    f32x4 acc[4][4];
#pragma unroll
    for (int a = 0; a < 4; ++a)
#pragma unroll
        for (int b = 0; b < 4; ++b) acc[a][b] = f32x4{0.f, 0.f, 0.f, 0.f};

    for (int k0 = 0; k0 < K; k0 += 32) {
        bf16x8 av[4], bv[4];
#pragma unroll
        for (int ja = 0; ja < 4; ++ja) av[ja] = *reinterpret_cast<const bf16x8*>(xrow[ja] + k0);
#pragma unroll
        for (int jb = 0; jb < 4; ++jb) bv[jb] = *reinterpret_cast<const bf16x8*>(wrow + jb * wstep + k0);
#pragma unroll
        for (int ja = 0; ja < 4; ++ja)
#pragma unroll
            for (int jb = 0; jb < 4; ++jb)
                acc[ja][jb] = __builtin_amdgcn_mfma_f32_16x16x32_bf16(av[ja], bv[jb], acc[ja][jb], 0, 0, 0);
    }

#pragma unroll
    for (int ja = 0; ja < 4; ++ja)
#pragma unroll
        for (int q = 0; q < 4; ++q) {
            int row = m0 + ja * 16 + g4 + q;
            if (row < Nn) {
#pragma unroll
                for (int jb = 0; jb < 4; ++jb)
                    Hout[(size_t)row * F + f0 + jb * 16 + r] = f2bf(acc[ja][jb][q]);
            }
        }

    float ps[4][4], pd[4][4];
#pragma unroll
    for (int ja = 0; ja < 4; ++ja)
#pragma unroll
        for (int q = 0; q < 4; ++q) { ps[ja][q] = 0.f; pd[ja][q] = 0.f; }
#pragma unroll
    for (int jb = 0; jb < 4; ++jb) {
        float ws_ = aSrc[f0 + jb * 16 + r];
        float wd_ = aDst[f0 + jb * 16 + r];
#pragma unroll
        for (int ja = 0; ja < 4; ++ja)
#pragma unroll
            for (int q = 0; q < 4; ++q) {
                ps[ja][q] += acc[ja][jb][q] * ws_;
                pd[ja][q] += acc[ja][jb][q] * wd_;
            }
    }
#pragma unroll
    for (int off = 1; off < 16; off <<= 1)
#pragma unroll
        for (int ja = 0; ja < 4; ++ja)
#pragma unroll
            for (int q = 0; q < 4; ++q) {
                ps[ja][q] += __shfl_xor(ps[ja][q], off, 64);
                pd[ja][q] += __shfl_xor(pd[ja][q], off, 64);
            }
    if (r == 0) {
        int Hh = F >> 6;
#pragma unroll
        for (int ja = 0; ja < 4; ++ja)
#pragma unroll
            for (int q = 0; q < 4; ++q) {
                int n = m0 + ja * 16 + g4 + q;
                if (n < Nn) {
                    a_s[(size_t)n * Hh + ft] = ps[ja][q];
                    a_d[(size_t)n * Hh + ft] = pd[ja][q];
                }
            }
    }
}

// ---------------- softmax + weighted aggregation (bucket CSR) ----------------
template<int H>
__global__ void aggregate_kernel(const unsigned short* __restrict__ Hb,
                                 const float* __restrict__ a_s, const float* __restrict__ a_d,
                                 const int* __restrict__ cnt, const int* __restrict__ bucket,
                                 const int* __restrict__ ovd, const int* __restrict__ ovs,
                                 const int* __restrict__ n_over,
                                 const float* __restrict__ bias,
                                 unsigned short* __restrict__ out, int Nn)
{
    constexpr int F = H * 64;
    constexpr int VEC = F / 64;
    __shared__ uint2 s_pk[4][64][H];
    int w = threadIdx.x >> 6;
    int node = blockIdx.x * 4 + w;
    int lane = threadIdx.x & 63;
    if (node >= Nn) return;
    int deg = cnt[node];

    float adn[H];
#pragma unroll
    for (int h = 0; h < H; ++h) adn[h] = a_d[(size_t)node * H + h];

    if (deg <= 64) {
        // -------- fast path: whole neighborhood in lane registers --------
        bool act = lane < deg;
        int sn = act ? bucket[(size_t)node * 64 + lane] : 0;
        float v[H];
        if (H == 4) {
            const f32x4 av = *reinterpret_cast<const f32x4*>(a_s + (size_t)sn * 4);
#pragma unroll
            for (int h = 0; h < 4; ++h) {
                float t = av[h] + adn[h];
                t = (t > 0.f) ? t : NEG_SLOPE * t;
                v[h] = act ? t : -1e30f;
            }
        } else {
            float t = a_s[sn] + adn[0];
            t = (t > 0.f) ? t : NEG_SLOPE * t;
            v[0] = act ? t : -1e30f;
        }
        float m[H], e[H], s[H];
#pragma unroll
        for (int h = 0; h < H; ++h) {
            m[h] = v[h];
#pragma unroll
            for (int off = 32; off >= 1; off >>= 1)
                m[h] = fmaxf(m[h], __shfl_xor(m[h], off, 64));
        }
#pragma unroll
        for (int h = 0; h < H; ++h) {
            e[h] = act ? __expf(v[h] - m[h]) : 0.f;
            s[h] = e[h];
#pragma unroll
            for (int off = 32; off >= 1; off >>= 1)
                s[h] += __shfl_xor(s[h], off, 64);
        }

        // stage packed (src, exp) per head in LDS (own-wave slice; no barrier needed)
#pragma unroll
        for (int h = 0; h < H; ++h)
            s_pk[w][lane][h] = make_uint2((unsigned int)sn, __float_as_uint(e[h]));
        asm volatile("s_waitcnt lgkmcnt(0)" ::: "memory");

        if (H == 4) {
            // 8 edges / iter (2 batches of 4): 16 lanes per edge, 16 ch/lane
            int laneq = lane & 15, qtr = lane >> 4, hd = laneq >> 2;
            float2 acc2[8];
#pragma unroll
            for (int k = 0; k < 8; ++k) acc2[k] = make_float2(0.f, 0.f);
            int j = 0;
            for (; j + 8 <= deg; j += 8) {
                uint2 pkA = s_pk[w][j + qtr][hd];
                uint2 pkB = s_pk[w][j + 4 + qtr][hd];
                const uint4* hpA = reinterpret_cast<const uint4*>(Hb + (size_t)pkA.x * 256 + laneq * 16);
                const uint4* hpB = reinterpret_cast<const uint4*>(Hb + (size_t)pkB.x * 256 + laneq * 16);
                uint4 a0 = hpA[0];
                uint4 a1 = hpA[1];
                uint4 b0 = hpB[0];
                uint4 b1 = hpB[1];
                float exA = __uint_as_float(pkA.y);
                float exB = __uint_as_float(pkB.y);
                fma2(acc2[0], exA, a0.x); fma2(acc2[1], exA, a0.y);
                fma2(acc2[2], exA, a0.z); fma2(acc2[3], exA, a0.w);
                fma2(acc2[4], exA, a1.x); fma2(acc2[5], exA, a1.y);
                fma2(acc2[6], exA, a1.z); fma2(acc2[7], exA, a1.w);
                fma2(acc2[0], exB, b0.x); fma2(acc2[1], exB, b0.y);
                fma2(acc2[2], exB, b0.z); fma2(acc2[3], exB, b0.w);
                fma2(acc2[4], exB, b1.x); fma2(acc2[5], exB, b1.y);
                fma2(acc2[6], exB, b1.z); fma2(acc2[7], exB, b1.w);
            }
            for (; j < deg; j += 4) {
                uint2 pk = s_pk[w][j + qtr][hd];
                float ex = __uint_as_float(pk.y);
                const uint4* hp = reinterpret_cast<const uint4*>(Hb + (size_t)pk.x * 256 + laneq * 16);
                uint4 u0 = hp[0];
                uint4 u1 = hp[1];
                fma2(acc2[0], ex, u0.x); fma2(acc2[1], ex, u0.y);
                fma2(acc2[2], ex, u0.z); fma2(acc2[3], ex, u0.w);
                fma2(acc2[4], ex, u1.x); fma2(acc2[5], ex, u1.y);
                fma2(acc2[6], ex, u1.z); fma2(acc2[7], ex, u1.w);
            }
#pragma unroll
            for (int k = 0; k < 8; ++k) {
                acc2[k].x += __shfl_xor(acc2[k].x, 32, 64);
                acc2[k].y += __shfl_xor(acc2[k].y, 32, 64);
                acc2[k].x += __shfl_xor(acc2[k].x, 16, 64);
                acc2[k].y += __shfl_xor(acc2[k].y, 16, 64);
            }
            if (lane < 16) {
                int hd2 = lane >> 2;
                float sh = (hd2 == 0) ? s[0] : (hd2 == 1) ? s[1] : (hd2 == 2) ? s[2] : s[3];
                float inv = 1.f / (sh + 1e-16f);
                unsigned int pk8[8];
#pragma unroll
                for (int k = 0; k < 8; ++k) {
                    float t0 = acc2[k].x * inv + bias[lane * 16 + 2 * k];
                    float t1 = acc2[k].y * inv + bias[lane * 16 + 2 * k + 1];
                    unsigned int lo = f2bf(t0 > 0.f ? t0 : 0.f);
                    unsigned int hi = f2bf(t1 > 0.f ? t1 : 0.f);
                    pk8[k] = lo | (hi << 16);
                }
                uint4* op = reinterpret_cast<uint4*>(out + (size_t)node * 256 + lane * 16);
                op[0] = make_uint4(pk8[0], pk8[1], pk8[2], pk8[3]);
                op[1] = make_uint4(pk8[4], pk8[5], pk8[6], pk8[7]);
            }
        } else {
            // 16 edges / iter (2 batches of 8): 8 lanes per edge, 8 ch/lane
            int laneo = lane & 7, oct = lane >> 3;
            float2 acc2[4];
#pragma unroll
            for (int k = 0; k < 4; ++k) acc2[k] = make_float2(0.f, 0.f);
            int j = 0;
            for (; j + 16 <= deg; j += 16) {
                uint2 pkA = s_pk[w][j + oct][0];
                uint2 pkB = s_pk[w][j + 8 + oct][0];
                const uint4 a = *reinterpret_cast<const uint4*>(Hb + (size_t)pkA.x * 64 + laneo * 8);
                const uint4 b = *reinterpret_cast<const uint4*>(Hb + (size_t)pkB.x * 64 + laneo * 8);
                float exA = __uint_as_float(pkA.y);
                float exB = __uint_as_float(pkB.y);
                fma2(acc2[0], exA, a.x); fma2(acc2[1], exA, a.y);
                fma2(acc2[2], exA, a.z); fma2(acc2[3], exA, a.w);
                fma2(acc2[0], exB, b.x); fma2(acc2[1], exB, b.y);
                fma2(acc2[2], exB, b.z); fma2(acc2[3], exB, b.w);
            }
            for (; j < deg; j += 8) {
                uint2 pk = s_pk[w][j + oct][0];
                float ex = __uint_as_float(pk.y);
                const uint4 u = *reinterpret_cast<const uint4*>(Hb + (size_t)pk.x * 64 + laneo * 8);
                fma2(acc2[0], ex, u.x); fma2(acc2[1], ex, u.y);
                fma2(acc2[2], ex, u.z); fma2(acc2[3], ex, u.w);
            }
#pragma unroll
            for (int k = 0; k < 4; ++k) {
                acc2[k].x += __shfl_xor(acc2[k].x, 32, 64);
                acc2[k].y += __shfl_xor(acc2[k].y, 32, 64);
                acc2[k].x += __shfl_xor(acc2[k].x, 16, 64);
                acc2[k].y += __shfl_xor(acc2[k].y, 16, 64);
                acc2[k].x += __shfl_xor(acc2[k].x, 8, 64);
                acc2[k].y += __shfl_xor(acc2[k].y, 8, 64);
            }
            if (lane < 8) {
                float inv = 1.f / (s[0] + 1e-16f);
                unsigned int pk4[4];
#pragma unroll
                for (int k = 0; k < 4; ++k) {
                    float t0 = acc2[k].x * inv + bias[lane * 8 + 2 * k];
                    float t1 = acc2[k].y * inv + bias[lane * 8 + 2 * k + 1];
                    unsigned int lo = f2bf(t0 > 0.f ? t0 : 0.f);
                    unsigned int hi = f2bf(t1 > 0.f ? t1 : 0.f);
                    pk4[k] = lo | (hi << 16);
                }
                *reinterpret_cast<uint4*>(out + (size_t)node * 64 + lane * 8) =
                    make_uint4(pk4[0], pk4[1], pk4[2], pk4[3]);
            }
        }
        return;
    }

    // -------- slow path (deg > 64): bucket (64 entries) + overflow list; exact --------
    int nov = *n_over;
    int head = (H == 1) ? 0 : (lane >> 4);
    float m[H], s[H];
#pragma unroll
    for (int h = 0; h < H; ++h) { m[h] = -1e30f; s[h] = 0.f; }
    {
        int sn = bucket[(size_t)node * 64 + lane];
#pragma unroll
        for (int h = 0; h < H; ++h) {
            float t = a_s[(size_t)sn * H + h] + adn[h];
            t = (t > 0.f) ? t : NEG_SLOPE * t;
            m[h] = fmaxf(m[h], t);
        }
    }
    for (int i = lane; i < nov; i += 64) {
        if (ovd[i] != node) continue;
        int sn = ovs[i];
#pragma unroll
        for (int h = 0; h < H; ++h) {
            float t = a_s[(size_t)sn * H + h] + adn[h];
            t = (t > 0.f) ? t : NEG_SLOPE * t;
            m[h] = fmaxf(m[h], t);
        }
    }
#pragma unroll
    for (int off = 32; off >= 1; off >>= 1)
#pragma unroll
        for (int h = 0; h < H; ++h) m[h] = fmaxf(m[h], __shfl_xor(m[h], off, 64));
    {
        int sn = bucket[(size_t)node * 64 + lane];
#pragma unroll
        for (int h = 0; h < H; ++h) {
            float t = a_s[(size_t)sn * H + h] + adn[h];
            t = (t > 0.f) ? t : NEG_SLOPE * t;
            s[h] += __expf(t - m[h]);
        }
    }
    for (int i = lane; i < nov; i += 64) {
        if (ovd[i] != node) continue;
        int sn = ovs[i];
#pragma unroll
        for (int h = 0; h < H; ++h) {
            float t = a_s[(size_t)sn * H + h] + adn[h];
            t = (t > 0.f) ? t : NEG_SLOPE * t;
            s[h] += __expf(t - m[h]);
        }
    }
#pragma unroll
    for (int off = 32; off >= 1; off >>= 1)
#pragma unroll
        for (int h = 0; h < H; ++h) s[h] += __shfl_xor(s[h], off, 64);

    float mh, sh, adh;
    if (H == 1) { mh = m[0]; sh = s[0]; adh = adn[0]; }
    else {
        mh  = (head == 0) ? m[0]   : (head == 1) ? m[1]   : (head == 2) ? m[2]   : m[3];
        sh  = (head == 0) ? s[0]   : (head == 1) ? s[1]   : (head == 2) ? s[2]   : s[3];
        adh = (head == 0) ? adn[0] : (head == 1) ? adn[1] : (head == 2) ? adn[2] : adn[3];
    }
    float inv = 1.f / (sh + 1e-16f);
    float acc[VEC];
#pragma unroll
    for (int k = 0; k < VEC; ++k) acc[k] = 0.f;
    for (int j = 0; j < 64; ++j) {
        int sn = bucket[(size_t)node * 64 + j];
        float t = a_s[(size_t)sn * H + head] + adh;
        t = (t > 0.f) ? t : NEG_SLOPE * t;
        float ex = __expf(t - mh);
        const unsigned short* hp = Hb + (size_t)sn * F + lane * VEC;
#pragma unroll
        for (int k = 0; k < VEC; ++k) acc[k] += ex * bf2f(hp[k]);
    }
    for (int i = 0; i < nov; ++i) {
        if (ovd[i] != node) continue;
        int sn = ovs[i];
        float t = a_s[(size_t)sn * H + head] + adh;
        t = (t > 0.f) ? t : NEG_SLOPE * t;
        float ex = __expf(t - mh);
        const unsigned short* hp = Hb + (size_t)sn * F + lane * VEC;
#pragma unroll
        for (int k = 0; k < VEC; ++k) acc[k] += ex * bf2f(hp[k]);
    }
#pragma unroll
    for (int k = 0; k < VEC; ++k) {
        int f = lane * VEC + k;
        float t = acc[k] * inv + bias[f];
        out[(size_t)node * F + f] = f2bf(t > 0.f ? t : 0.f);
    }
}

// ---------------- global mean pool (sums, bf16 input) ----------------
__global__ void pool_kernel(const unsigned short* __restrict__ x, const int* __restrict__ batch,
                            float* __restrict__ gsums, int Nn)
{
    int lane = threadIdx.x;        // blockDim = 64
    int n0 = blockIdx.x * 64;
    if (n0 >= Nn) return;
    int nend = min(n0 + 64, Nn);
    float acc = 0.f;
    int gcur = batch[n0];
    for (int n = n0; n < nend; ++n) {
        int g = batch[n];
        if (g != gcur) {
            atomicAdd(&gsums[gcur * 64 + lane], acc);
            acc = 0.f;
            gcur = g;
        }
        acc += bf2f(x[(size_t)n * 64 + lane]);
    }
    atomicAdd(&gsums[gcur * 64 + lane], acc);
}

// ---------------- final linear ----------------
__global__ void final_kernel(const float* __restrict__ gsums, const int* __restrict__ gcnt,
                             const float* __restrict__ linW, const float* __restrict__ linb,
                             float* __restrict__ out, int G)
{
    int t = threadIdx.x;
    if (t >= G * 10) return;
    int g = t / 10, j = t % 10;
    float cnt = (float)max(gcnt[g], 1);
    float acc = 0.f;
#pragma unroll
    for (int c = 0; c < 64; ++c) acc += gsums[g * 64 + c] * linW[j * 64 + c];
    out[g * 10 + j] = acc / cnt + linb[j];
}

extern "C" void kernel_launch(void* const* d_in, const int* in_sizes, int n_in,
                              void* d_out, int out_size, void* d_ws, size_t ws_size,
                              hipStream_t stream)
{
    const int*   x_ids    = (const int*)d_in[0];
    const float* degrees  = (const float*)d_in[1];
    const int*   edge_src = (const int*)d_in[2];
    const int*   edge_dst = (const int*)d_in[3];
    const int*   batch    = (const int*)d_in[4];
    const float* emb      = (const float*)d_in[5];
    const float* W1  = (const float*)d_in[6];
    const float* as1 = (const float*)d_in[7];
    const float* ad1 = (const float*)d_in[8];
    const float* b1  = (const float*)d_in[9];
    const float* W2  = (const float*)d_in[10];
    const float* as2 = (const float*)d_in[11];
    const float* ad2 = (const float*)d_in[12];
    const float* b2  = (const float*)d_in[13];
    const float* W3  = (const float*)d_in[14];
    const float* as3 = (const float*)d_in[15];
    const float* ad3 = (const float*)d_in[16];
    const float* b3  = (const float*)d_in[17];
    const float* linW = (const float*)d_in[18];
    const float* linb = (const float*)d_in[19];

    const int N  = in_sizes[0];
    const int E0 = in_sizes[2];
    const int E2 = E0 + N;
    const int G  = out_size / 10;
    const int nW1 = in_sizes[6], nW2 = in_sizes[10], nW3 = in_sizes[14];

    char* p = (char*)d_ws;
    size_t off = 0;
    auto take = [&](size_t bytes) {
        void* q = p + off;
        off = (off + bytes + 255) & ~(size_t)255;
        return q;
    };
    unsigned short* xA  = (unsigned short*)take((size_t)N * 256 * 2);
    unsigned short* xB  = (unsigned short*)take((size_t)N * 256 * 2);
    float* a_s     = (float*)take((size_t)N * 4 * 4);
    float* a_d     = (float*)take((size_t)N * 4 * 4);
    int*   cnt     = (int*)take((size_t)(N + 64) * 4);   // cnt[N] followed by n_over
    int*   n_over  = cnt + N;
    int*   bucket  = (int*)take((size_t)N * 64 * 4);
    int*   ovd     = (int*)take((size_t)E2 * 4);
    int*   ovs     = (int*)take((size_t)E2 * 4);
    float* gsums   = (float*)take((size_t)G * 64 * 4);
    int*   gcnt    = (int*)take((size_t)G * 4);
    unsigned short* w1b = (unsigned short*)take((size_t)nW1 * 2);
    unsigned short* w2b = (unsigned short*)take((size_t)nW2 * 2);
    unsigned short* w3b = (unsigned short*)take((size_t)nW3 * 2);

    hipMemsetAsync(gsums, 0, (size_t)G * 64 * 4, stream);

    const int nodeBlocks4 = (N + 3) / 4;

    // prep block partition
    const int nWtot = nW1 + nW2 + nW3;
    const int bW = (nWtot + 255) / 256;
    const int bX = bW + nodeBlocks4;
    prep_kernel<<<bX + 1, 256, 0, stream>>>(W1, nW1, W2, nW2, W3, nW3, w1b, w2b, w3b,
                                            x_ids, degrees, emb, xA,
                                            cnt, bucket, n_over, batch, gcnt,
                                            N, G, bW, bX);

    const int mtiles = (N + 63) / 64;
    auto gemmBlocks = [&](int ftiles) { return (mtiles * ftiles + 3) / 4; };

    // ---- layer 1 (fused with edge scatter): 64 -> 4x64 concat ----
    const int gemmB1   = gemmBlocks(4);
    const int scatterB = (E0 + 1023) / 1024;
    gemm_scatter<<<gemmB1 + scatterB, 256, 0, stream>>>(xA, w1b, xB, as1, ad1, a_s, a_d,
                                                        N, 64, 256, gemmB1,
                                                        edge_src, edge_dst, cnt, bucket,
                                                        ovd, ovs, n_over, E0);
    aggregate_kernel<4><<<nodeBlocks4, 256, 0, stream>>>(xB, a_s, a_d, cnt, bucket, ovd, ovs, n_over, b1, xA, N);
    // ---- layer 2: 256 -> 4x64 concat ----
    gemm_mfma<<<gemmBlocks(4), 256, 0, stream>>>(xA, w2b, xB, as2, ad2, a_s, a_d, N, 256, 256);
    aggregate_kernel<4><<<nodeBlocks4, 256, 0, stream>>>(xB, a_s, a_d, cnt, bucket, ovd, ovs, n_over, b2, xA, N);
    // ---- layer 3: 256 -> 1x64 (mean == identity) ----
    gemm_mfma<<<gemmBlocks(1), 256, 0, stream>>>(xA, w3b, xB, as3, ad3, a_s, a_d, N, 256, 64);
    aggregate_kernel<1><<<nodeBlocks4, 256, 0, stream>>>(xB, a_s, a_d, cnt, bucket, ovd, ovs, n_over, b3, xA, N);

    pool_kernel<<<(N + 63) / 64, 64, 0, stream>>>(xA, batch, gsums, N);
    final_kernel<<<1, ((G * 10 + 63) / 64) * 64, 0, stream>>>(gsums, gcnt, linW, linb, (float*)d_out, G);
}